// Round 18
// baseline (1357.527 us; speedup 1.0000x reference)
//
#include <hip/hip_runtime.h>
#include <math.h>

#define LSEQ   2048
#define NROWS  8192      // B*L = 4*2048
#define DMODEL 1024
#define DINNER 2048
#define NH     32
#define CONVD  2176
#define NPROJ  4256
#define NPROJ_PAD 4352
#define EPSV   1e-5f
#define SEGS   16
#define TSEG   128       // chunk length

typedef __bf16 bf16x8_t __attribute__((ext_vector_type(8)));
typedef float f32x4_t __attribute__((ext_vector_type(4)));
typedef unsigned short u16x8_t __attribute__((ext_vector_type(8)));

__device__ __forceinline__ unsigned short f2bf(float f) {
  unsigned int u = __float_as_uint(f);
  u += 0x7fffu + ((u >> 16) & 1u);
  return (unsigned short)(u >> 16);
}
__device__ __forceinline__ float bf2f(unsigned short u) {
  return __uint_as_float((unsigned int)u << 16);
}
__device__ __forceinline__ float siluf(float x) { return x / (1.f + expf(-x)); }

// async global->LDS, 16B per lane. LDS dest must be wave-uniform base + lane*16.
__device__ __forceinline__ void gload16(const unsigned short* g, unsigned short* l) {
  __builtin_amdgcn_global_load_lds(
      (const __attribute__((address_space(1))) void*)g,
      (__attribute__((address_space(3))) void*)l, 16, 0, 0);
}

// ---------------- LayerNorm + cast to bf16 ----------------
__global__ __launch_bounds__(256) void ln_kernel(const float* __restrict__ X,
    const float* __restrict__ w, const float* __restrict__ b,
    unsigned short* __restrict__ out)
{
  const int r = blockIdx.x, tid = threadIdx.x;
  __shared__ float red[4];
  const float4 v = ((const float4*)(X + (size_t)r * DMODEL))[tid];
  float s = v.x + v.y + v.z + v.w;
#pragma unroll
  for (int o = 32; o > 0; o >>= 1) s += __shfl_down(s, o);
  if ((tid & 63) == 0) red[tid >> 6] = s;
  __syncthreads();
  const float mu = (red[0] + red[1] + red[2] + red[3]) * (1.f / DMODEL);
  __syncthreads();
  const float dx = v.x - mu, dy = v.y - mu, dz = v.z - mu, dw = v.w - mu;
  float ss = dx * dx + dy * dy + dz * dz + dw * dw;
#pragma unroll
  for (int o = 32; o > 0; o >>= 1) ss += __shfl_down(ss, o);
  if ((tid & 63) == 0) red[tid >> 6] = ss;
  __syncthreads();
  const float var = (red[0] + red[1] + red[2] + red[3]) * (1.f / DMODEL);
  const float rs = rsqrtf(var + EPSV);
  const float4 wv = ((const float4*)w)[tid];
  const float4 bv = ((const float4*)b)[tid];
  const size_t d = (size_t)r * DMODEL + tid * 4;
  out[d + 0] = f2bf(dx * rs * wv.x + bv.x);
  out[d + 1] = f2bf(dy * rs * wv.y + bv.y);
  out[d + 2] = f2bf(dz * rs * wv.z + bv.z);
  out[d + 3] = f2bf(dw * rs * wv.w + bv.w);
}

// ---------------- transpose fp32 (K x N) -> bf16 (N x K) ----------------
__global__ void transpose_bf16(const float* __restrict__ W,
    unsigned short* __restrict__ WT, int K, int N)
{
  __shared__ float t[32][33];
  const int n0 = blockIdx.x * 32, k0 = blockIdx.y * 32;
  const int tx = threadIdx.x, ty = threadIdx.y;
  if (n0 + tx < N) t[ty][tx] = W[(size_t)(k0 + ty) * N + n0 + tx];
  __syncthreads();
  if (n0 + ty < N) WT[(size_t)(n0 + ty) * K + k0 + tx] = f2bf(t[tx][ty]);
}

#define WAITBAR(N) do {                                          \
    __builtin_amdgcn_sched_barrier(0);                           \
    asm volatile("s_waitcnt vmcnt(" #N ")" ::: "memory");        \
    __builtin_amdgcn_s_barrier();                                \
    __builtin_amdgcn_sched_barrier(0);                           \
  } while (0)

#define BAR do {                                 \
    __builtin_amdgcn_sched_barrier(0);           \
    __builtin_amdgcn_s_barrier();                \
    __builtin_amdgcn_sched_barrier(0);           \
  } while (0)

// ---------------- bf16 MFMA GEMM (128x128 tile, 2-deep counted-vmcnt) ----------
// C[M,N] = A[M,K] * BT[N,K]^T. 4 waves (2x2), 4x4 frags/wave. GEMM1 (bf16 out).
#define STAGE(BUF, KT) do {                                        \
    const int kt_ = (KT) * 32;                                     \
    gload16(Ag + kt_,                  sA##BUF + tid * 8);         \
    gload16(Ag + (size_t)64 * K + kt_, sA##BUF + 2048 + tid * 8);  \
    gload16(Bg + kt_,                  sB##BUF + tid * 8);         \
    gload16(Bg + (size_t)64 * K + kt_, sB##BUF + 2048 + tid * 8);  \
  } while (0)

#define COMPUTE(BUF) do {                                                           \
    bf16x8_t af[4], bfr[4];                                                         \
    _Pragma("unroll")                                                               \
    for (int mi = 0; mi < 4; ++mi)                                                  \
      af[mi] = *(const bf16x8_t*)(sA##BUF + (wr * 64 + mi * 16 + la) * 32 + lb * 8);\
    _Pragma("unroll")                                                               \
    for (int ni = 0; ni < 4; ++ni)                                                  \
      bfr[ni] = *(const bf16x8_t*)(sB##BUF + (wc * 64 + ni * 16 + la) * 32 + lb * 8);\
    _Pragma("unroll")                                                               \
    for (int mi = 0; mi < 4; ++mi)                                                  \
      _Pragma("unroll")                                                             \
      for (int ni = 0; ni < 4; ++ni)                                                \
        acc[mi][ni] = __builtin_amdgcn_mfma_f32_16x16x32_bf16(af[mi], bfr[ni],      \
                                                              acc[mi][ni], 0, 0, 0);\
  } while (0)

__global__ __launch_bounds__(256) void gemm_bf16(
    const unsigned short* __restrict__ A,
    const unsigned short* __restrict__ BT,
    unsigned short* __restrict__ Cb,
    int N, int K, int ldc)
{
  __shared__ __attribute__((aligned(16))) unsigned short sA0[128 * 32];
  __shared__ __attribute__((aligned(16))) unsigned short sA1[128 * 32];
  __shared__ __attribute__((aligned(16))) unsigned short sB0[128 * 32];
  __shared__ __attribute__((aligned(16))) unsigned short sB1[128 * 32];
  const int tid = threadIdx.x;
  const int w = tid >> 6, l = tid & 63;
  const int wr = w >> 1, wc = w & 1;
  const int la = l & 15, lb = l >> 4;
  const int m0 = blockIdx.x * 128, n0 = blockIdx.y * 128;
  f32x4_t acc[4][4];
#pragma unroll
  for (int i = 0; i < 4; ++i)
#pragma unroll
    for (int j = 0; j < 4; ++j) acc[i][j] = (f32x4_t){0.f, 0.f, 0.f, 0.f};

  const int r0 = tid >> 2, q0 = tid & 3;
  const unsigned short* Ag = A + (size_t)(m0 + r0) * K + q0 * 8;
  const unsigned short* Bg = BT + (size_t)(n0 + r0) * K + q0 * 8;
  const int nkt = K / 32;

  STAGE(0, 0);
  STAGE(1, 1);

  for (int t = 0; t < nkt - 2; t += 2) {
    WAITBAR(4);
    COMPUTE(0);
    BAR;
    STAGE(0, t + 2);
    WAITBAR(4);
    COMPUTE(1);
    BAR;
    STAGE(1, t + 3);
  }
  WAITBAR(4);
  COMPUTE(0);
  WAITBAR(0);
  COMPUTE(1);

#pragma unroll
  for (int mi = 0; mi < 4; ++mi) {
#pragma unroll
    for (int ni = 0; ni < 4; ++ni) {
      const int col = n0 + wc * 64 + ni * 16 + la;
      if (col < N) {
#pragma unroll
        for (int r = 0; r < 4; ++r) {
          const int row = m0 + wr * 64 + mi * 16 + lb * 4 + r;
          Cb[(size_t)row * ldc + col] = f2bf(acc[mi][ni][r]);
        }
      }
    }
  }
}

// ---------------- GEMM2: K-split x2, fp32 atomic residual accumulate ------------
// C[M,N] += A[M,K]*BT[N,K]^T, blockIdx.z selects K-half (grid 64x8x2 = 4 blk/CU).
__global__ __launch_bounds__(256) void gemm_res(
    const unsigned short* __restrict__ A,
    const unsigned short* __restrict__ BT,
    float* __restrict__ Cf,
    int N, int Kfull, int ldc)
{
  __shared__ __attribute__((aligned(16))) unsigned short sA0[128 * 32];
  __shared__ __attribute__((aligned(16))) unsigned short sA1[128 * 32];
  __shared__ __attribute__((aligned(16))) unsigned short sB0[128 * 32];
  __shared__ __attribute__((aligned(16))) unsigned short sB1[128 * 32];
  const int tid = threadIdx.x;
  const int w = tid >> 6, l = tid & 63;
  const int wr = w >> 1, wc = w & 1;
  const int la = l & 15, lb = l >> 4;
  const int m0 = blockIdx.x * 128, n0 = blockIdx.y * 128;
  const int K = Kfull;                       // row stride
  const int k0 = blockIdx.z * (Kfull >> 1);  // this block's K-half start
  f32x4_t acc[4][4];
#pragma unroll
  for (int i = 0; i < 4; ++i)
#pragma unroll
    for (int j = 0; j < 4; ++j) acc[i][j] = (f32x4_t){0.f, 0.f, 0.f, 0.f};

  const int r0 = tid >> 2, q0 = tid & 3;
  const unsigned short* Ag = A + (size_t)(m0 + r0) * K + k0 + q0 * 8;
  const unsigned short* Bg = BT + (size_t)(n0 + r0) * K + k0 + q0 * 8;
  const int nkt = (Kfull >> 1) / 32;         // 32 for K=2048

  STAGE(0, 0);
  STAGE(1, 1);

  for (int t = 0; t < nkt - 2; t += 2) {
    WAITBAR(4);
    COMPUTE(0);
    BAR;
    STAGE(0, t + 2);
    WAITBAR(4);
    COMPUTE(1);
    BAR;
    STAGE(1, t + 3);
  }
  WAITBAR(4);
  COMPUTE(0);
  WAITBAR(0);
  COMPUTE(1);

#pragma unroll
  for (int mi = 0; mi < 4; ++mi) {
#pragma unroll
    for (int ni = 0; ni < 4; ++ni) {
      const int col = n0 + wc * 64 + ni * 16 + la;
      if (col < N) {
#pragma unroll
        for (int r = 0; r < 4; ++r) {
          const int row = m0 + wr * 64 + mi * 16 + lb * 4 + r;
          atomicAdd(&Cf[(size_t)row * ldc + col], acc[mi][ni][r]);
        }
      }
    }
  }
}

// ---------------- causal depthwise conv (width 4) + silu, 4 rows/block ----------
__global__ __launch_bounds__(256) void conv_kernel(const unsigned short* __restrict__ zx,
    const float* __restrict__ cw, const float* __restrict__ cb,
    unsigned short* __restrict__ out)
{
  const int c8 = (blockIdx.x * 256 + threadIdx.x) * 8;
  if (c8 >= CONVD) return;
  const int r4 = blockIdx.y * 4;           // first output row
  const int l4 = r4 & (LSEQ - 1);          // position within batch
  float vin[7][8];
#pragma unroll
  for (int i = 0; i < 7; ++i) {
    if (l4 - 3 + i >= 0) {
      const u16x8_t v = *(const u16x8_t*)(zx + (size_t)(r4 - 3 + i) * NPROJ + DINNER + c8);
#pragma unroll
      for (int e = 0; e < 8; ++e) vin[i][e] = bf2f(v[e]);
    } else {
#pragma unroll
      for (int e = 0; e < 8; ++e) vin[i][e] = 0.f;
    }
  }
  float wk[4][8], bias[8];
  {
    const float4 b0 = *(const float4*)(cb + c8);
    const float4 b1 = *(const float4*)(cb + c8 + 4);
    bias[0]=b0.x; bias[1]=b0.y; bias[2]=b0.z; bias[3]=b0.w;
    bias[4]=b1.x; bias[5]=b1.y; bias[6]=b1.z; bias[7]=b1.w;
#pragma unroll
    for (int k = 0; k < 4; ++k) {
      const float4 w0 = *(const float4*)(cw + k * CONVD + c8);
      const float4 w1 = *(const float4*)(cw + k * CONVD + c8 + 4);
      wk[k][0]=w0.x; wk[k][1]=w0.y; wk[k][2]=w0.z; wk[k][3]=w0.w;
      wk[k][4]=w1.x; wk[k][5]=w1.y; wk[k][6]=w1.z; wk[k][7]=w1.w;
    }
  }
#pragma unroll
  for (int rr = 0; rr < 4; ++rr) {
    float acc[8];
#pragma unroll
    for (int e = 0; e < 8; ++e) acc[e] = bias[e];
#pragma unroll
    for (int k = 0; k < 4; ++k)
#pragma unroll
      for (int e = 0; e < 8; ++e)
        acc[e] = fmaf(vin[rr + k][e], wk[k][e], acc[e]);
    u16x8_t o;
#pragma unroll
    for (int e = 0; e < 8; ++e) o[e] = f2bf(siluf(acc[e]));
    *(u16x8_t*)(out + (size_t)(r4 + rr) * CONVD + c8) = o;
  }
}

// ---------------- chunked SSD pass A (MFMA): intra-chunk Y + local end-state ----------------
// dt/softplus/log-decay folded in (wave 0). grid = 128 bh * 16 chunks, 256 thr.
// LDS 50KB (3 blocks/CU): Btw overlays CB rows 0..63 after Y1 consumes M.
#define CBB(t, cbyte)  ((char*)CB  + (t) * 256 + ((cbyte) ^ (((t) & 7) << 4)))
#define XTB(p, cbyte)  ((char*)Xt  + (p) * 256 + ((cbyte) ^ (((p) & 7) << 4)))
__global__ __launch_bounds__(256) void ssd_chunk_kernel(
    const unsigned short* __restrict__ xbc,   // NROWS x CONVD (xs | B | C)
    const unsigned short* __restrict__ zraw,  // NROWS x NPROJ (raw proj, dt col 4224+h)
    const float* __restrict__ dt_bias,
    const float* __restrict__ A_log,
    const float* __restrict__ Dp,
    unsigned short* __restrict__ y, int ldy,  // zxb+2048, NPROJ
    unsigned short* __restrict__ H,           // [SEGS][128][4096] (p*64+n)
    float* __restrict__ cumdec)               // [128][LSEQ]
{
  __shared__ unsigned short CB[TSEG * 128];   // C(0:64)|B(64:128) -> M -> Btw   32KB
  __shared__ unsigned short Xt[64 * TSEG];    // X^T [p][t]                      16KB
  __shared__ float cumS[TSEG], dtS[TSEG], wS[TSEG];
  const int id = blockIdx.x;
  const int bh = id >> 4, ch = id & 15;
  const int b = bh >> 5, h = bh & 31;
  const int tid = threadIdx.x;
  const int w = tid >> 6, l = tid & 63;
  const int la = l & 15, lb = l >> 4;
  const size_t row0 = (size_t)b * LSEQ + (size_t)ch * TSEG;
  const unsigned short* xr = xbc + row0 * CONVD;
  const float dp = Dp[h];

  // stage C, B (swizzled rows) and X^T
  {
    const int t = tid >> 1, q = tid & 1;
    const unsigned short* src = xr + (size_t)t * CONVD;
#pragma unroll
    for (int j = 0; j < 4; ++j) {
      const int c0 = q * 32 + j * 8;
      *(u16x8_t*)CBB(t, c0 * 2)       = *(const u16x8_t*)(src + 2112 + c0);  // C
      *(u16x8_t*)CBB(t, 128 + c0 * 2) = *(const u16x8_t*)(src + 2048 + c0);  // B
      const u16x8_t xv = *(const u16x8_t*)(src + h * 64 + c0);
#pragma unroll
      for (int e = 0; e < 8; ++e)
        *(unsigned short*)XTB(c0 + e, t * 2) = xv[e];
    }
  }
  if (w == 0) {  // dt softplus + log-decay + cumulative sums
    const float bias = dt_bias[h];
    const float aexp = __expf(A_log[h]);
    const float x0 = bf2f(zraw[(row0 + l) * NPROJ + (DINNER + CONVD) + h]) + bias;
    const float x1 = bf2f(zraw[(row0 + 64 + l) * NPROJ + (DINNER + CONVD) + h]) + bias;
    const float d0 = (x0 > 20.f) ? x0 : log1pf(__expf(x0));
    const float d1 = (x1 > 20.f) ? x1 : log1pf(__expf(x1));
    float a0 = -d0 * aexp;
    float a1 = -d1 * aexp;
#pragma unroll
    for (int o = 1; o < 64; o <<= 1) { const float u = __shfl_up(a0, o); if (l >= o) a0 += u; }
    const float tot0 = __shfl(a0, 63);
#pragma unroll
    for (int o = 1; o < 64; o <<= 1) { const float u = __shfl_up(a1, o); if (l >= o) a1 += u; }
    a1 += tot0;
    const float cT = __shfl(a1, 63);
    cumS[l] = a0;       cumS[64 + l] = a1;
    dtS[l] = d0;        dtS[64 + l] = d1;
    wS[l] = __expf(cT - a0) * d0;
    wS[64 + l] = __expf(cT - a1) * d1;
    float* cdg = cumdec + (size_t)bh * LSEQ + (size_t)ch * TSEG;
    cdg[l] = __expf(a0);
    cdg[64 + l] = __expf(a1);
  }
  __syncthreads();

  // G = C @ B^T : wave w owns rows [w*32, w*32+32)
  f32x4_t g[2][8];
#pragma unroll
  for (int mi = 0; mi < 2; ++mi)
#pragma unroll
    for (int ni = 0; ni < 8; ++ni) g[mi][ni] = (f32x4_t){0.f, 0.f, 0.f, 0.f};
#pragma unroll
  for (int ks = 0; ks < 2; ++ks) {
    bf16x8_t af[2], bfr[8];
#pragma unroll
    for (int mi = 0; mi < 2; ++mi)
      af[mi] = *(const bf16x8_t*)CBB(w * 32 + mi * 16 + la, ks * 64 + lb * 16);
#pragma unroll
    for (int ni = 0; ni < 8; ++ni)
      bfr[ni] = *(const bf16x8_t*)CBB(ni * 16 + la, 128 + ks * 64 + lb * 16);
#pragma unroll
    for (int mi = 0; mi < 2; ++mi)
#pragma unroll
      for (int ni = 0; ni < 8; ++ni)
        g[mi][ni] = __builtin_amdgcn_mfma_f32_16x16x32_bf16(af[mi], bfr[ni], g[mi][ni], 0, 0, 0);
  }
  __syncthreads();   // all CB reads done before M overwrites it

  // mask -> M (overwrites CB)
#pragma unroll
  for (int mi = 0; mi < 2; ++mi) {
#pragma unroll
    for (int ni = 0; ni < 8; ++ni) {
      const int s = ni * 16 + la;
#pragma unroll
      for (int r = 0; r < 4; ++r) {
        const int t = w * 32 + mi * 16 + lb * 4 + r;
        float mv = 0.f;
        if (s <= t) mv = g[mi][ni][r] * __expf(cumS[t] - cumS[s]) * dtS[s];
        if (s == t) mv += dp;
        *(unsigned short*)CBB(t, s * 2) = f2bf(mv);
      }
    }
  }
  __syncthreads();   // M visible to all waves

  // Y1 = M @ X : K = 128
  f32x4_t y1[2][4];
#pragma unroll
  for (int mi = 0; mi < 2; ++mi)
#pragma unroll
    for (int ni = 0; ni < 4; ++ni) y1[mi][ni] = (f32x4_t){0.f, 0.f, 0.f, 0.f};
#pragma unroll
  for (int ks = 0; ks < 4; ++ks) {
    bf16x8_t af[2], xf[4];
#pragma unroll
    for (int mi = 0; mi < 2; ++mi)
      af[mi] = *(const bf16x8_t*)CBB(w * 32 + mi * 16 + la, ks * 64 + lb * 16);
#pragma unroll
    for (int ni = 0; ni < 4; ++ni)
      xf[ni] = *(const bf16x8_t*)XTB(ni * 16 + la, ks * 64 + lb * 16);
#pragma unroll
    for (int mi = 0; mi < 2; ++mi)
#pragma unroll
      for (int ni = 0; ni < 4; ++ni)
        y1[mi][ni] = __builtin_amdgcn_mfma_f32_16x16x32_bf16(af[mi], xf[ni], y1[mi][ni], 0, 0, 0);
  }
  // write y while M region is being recycled
  unsigned short* yg = y + row0 * ldy + h * 64;
#pragma unroll
  for (int mi = 0; mi < 2; ++mi)
#pragma unroll
    for (int ni = 0; ni < 4; ++ni)
#pragma unroll
      for (int r = 0; r < 4; ++r) {
        const int t = w * 32 + mi * 16 + lb * 4 + r;
        yg[(size_t)t * ldy + ni * 16 + la] = f2bf(y1[mi][ni][r]);
      }
  __syncthreads();   // Y1 done reading CB (M dead)

  // Btw = (w_s * B)^T into CB rows 0..63 (global re-read, L2-hot)
  {
    const int s = tid >> 1, q = tid & 1;
    const unsigned short* src = xr + (size_t)s * CONVD + 2048;
    const float ww = wS[s];
#pragma unroll
    for (int j = 0; j < 4; ++j) {
      const int c0 = q * 32 + j * 8;
      const u16x8_t bv = *(const u16x8_t*)(src + c0);
#pragma unroll
      for (int e = 0; e < 8; ++e)
        *(unsigned short*)CBB(c0 + e, s * 2) = f2bf(bf2f(bv[e]) * ww);
    }
  }
  __syncthreads();   // Btw visible

  // Hloc = X^T @ Btw^T : K = 128
  f32x4_t hacc[4];
#pragma unroll
  for (int ni = 0; ni < 4; ++ni) hacc[ni] = (f32x4_t){0.f, 0.f, 0.f, 0.f};
#pragma unroll
  for (int ks = 0; ks < 4; ++ks) {
    const bf16x8_t af = *(const bf16x8_t*)XTB(w * 16 + la, ks * 64 + lb * 16);
    bf16x8_t bw[4];
#pragma unroll
    for (int ni = 0; ni < 4; ++ni)
      bw[ni] = *(const bf16x8_t*)CBB(ni * 16 + la, ks * 64 + lb * 16);
#pragma unroll
    for (int ni = 0; ni < 4; ++ni)
      hacc[ni] = __builtin_amdgcn_mfma_f32_16x16x32_bf16(af, bw[ni], hacc[ni], 0, 0, 0);
  }

  unsigned short* Hg = H + ((size_t)ch * 128 + bh) * 4096;
#pragma unroll
  for (int ni = 0; ni < 4; ++ni)
#pragma unroll
    for (int r = 0; r < 4; ++r) {
      const int p = w * 16 + lb * 4 + r;
      Hg[p * 64 + ni * 16 + la] = f2bf(hacc[ni][r]);
    }
}

// ---------------- scan pass 2: segment-summary scan (end-state -> start-state) ----------------
__global__ __launch_bounds__(256) void scan2_kernel(
    unsigned short* __restrict__ H, const float* __restrict__ cumdec)
{
  const int bh = blockIdx.x;
  const int e = threadIdx.x * 16;
  float hs[16];
#pragma unroll
  for (int k = 0; k < 16; ++k) hs[k] = 0.f;
  unsigned short* Hb = H + (size_t)bh * 4096 + e;
  const float* cd = cumdec + (size_t)bh * LSEQ;
  for (int s = 0; s < SEGS; ++s) {
    unsigned short* p = Hb + (size_t)s * 128 * 4096;
    const float rseg = cd[s * TSEG + TSEG - 1];
    u16x8_t v0 = *(u16x8_t*)p, v1 = *(u16x8_t*)(p + 8);
    u16x8_t w0, w1;
#pragma unroll
    for (int k = 0; k < 8; ++k) {
      const float tmp = bf2f(v0[k]);
      w0[k] = f2bf(hs[k]);
      hs[k] = fmaf(rseg, hs[k], tmp);
    }
#pragma unroll
    for (int k = 0; k < 8; ++k) {
      const float tmp = bf2f(v1[k]);
      w1[k] = f2bf(hs[k + 8]);
      hs[k + 8] = fmaf(rseg, hs[k + 8], tmp);
    }
    *(u16x8_t*)p = w0;
    *(u16x8_t*)(p + 8) = w1;
  }
}

// ---------------- scan pass 3 (MFMA): Y += diag(cumdec) * C @ Hstart^T ----------------
#define CSB(t, cbyte) ((char*)Cs + (t) * 128 + ((cbyte) ^ (((t) & 7) << 4)))
#define HSB(p, cbyte) ((char*)Hs + (p) * 128 + ((cbyte) ^ (((p) & 7) << 4)))
__global__ __launch_bounds__(256) void scan3_mfma(
    const unsigned short* __restrict__ xbc,
    const float* __restrict__ cumdec,
    const unsigned short* __restrict__ H,
    unsigned short* __restrict__ y, int ldy)
{
  __shared__ unsigned short Cs[TSEG * 64];  // 16KB
  __shared__ unsigned short Hs[64 * 64];    // 8KB
  __shared__ float cdS[TSEG];
  const int id = blockIdx.x;
  const int bh = id / 15, ch = id % 15 + 1;
  const int b = bh >> 5, h = bh & 31;
  const int tid = threadIdx.x, w = tid >> 6, l = tid & 63;
  const int la = l & 15, lb = l >> 4;
  const size_t row0 = (size_t)b * LSEQ + (size_t)ch * TSEG;
  const unsigned short* xr = xbc + row0 * CONVD;
  {
    const int t = tid >> 1, q = tid & 1;
#pragma unroll
    for (int j = 0; j < 4; ++j) {
      const int c0 = q * 32 + j * 8;
      *(u16x8_t*)CSB(t, c0 * 2) = *(const u16x8_t*)(xr + (size_t)t * CONVD + 2112 + c0);
    }
  }
  {
    const int p = tid >> 2, q = tid & 3;
    const unsigned short* hsrc = H + ((size_t)ch * 128 + bh) * 4096 + p * 64;
#pragma unroll
    for (int j = 0; j < 2; ++j) {
      const int c0 = q * 16 + j * 8;
      *(u16x8_t*)HSB(p, c0 * 2) = *(const u16x8_t*)(hsrc + c0);
    }
  }
  if (tid < TSEG) cdS[tid] = cumdec[(size_t)bh * LSEQ + (size_t)ch * TSEG + tid];
  __syncthreads();
  f32x4_t acc[2][4];
#pragma unroll
  for (int mi = 0; mi < 2; ++mi)
#pragma unroll
    for (int ni = 0; ni < 4; ++ni) acc[mi][ni] = (f32x4_t){0.f, 0.f, 0.f, 0.f};
#pragma unroll
  for (int ks = 0; ks < 2; ++ks) {
    bf16x8_t af[2], bfr[4];
#pragma unroll
    for (int mi = 0; mi < 2; ++mi)
      af[mi] = *(const bf16x8_t*)CSB(w * 32 + mi * 16 + la, ks * 64 + lb * 16);
#pragma unroll
    for (int ni = 0; ni < 4; ++ni)
      bfr[ni] = *(const bf16x8_t*)HSB(ni * 16 + la, ks * 64 + lb * 16);
#pragma unroll
    for (int mi = 0; mi < 2; ++mi)
#pragma unroll
      for (int ni = 0; ni < 4; ++ni)
        acc[mi][ni] = __builtin_amdgcn_mfma_f32_16x16x32_bf16(af[mi], bfr[ni], acc[mi][ni], 0, 0, 0);
  }
  unsigned short* yg = y + row0 * ldy + h * 64;
#pragma unroll
  for (int mi = 0; mi < 2; ++mi)
#pragma unroll
    for (int ni = 0; ni < 4; ++ni)
#pragma unroll
      for (int r = 0; r < 4; ++r) {
        const int t = w * 32 + mi * 16 + lb * 4 + r;
        unsigned short* yp = yg + (size_t)t * ldy + ni * 16 + la;
        *yp = f2bf(bf2f(*yp) + acc[mi][ni][r] * cdS[t]);
      }
}

// ---------------- y * silu(z), RMSNorm, * norm_w -> bf16 ----------------
__global__ __launch_bounds__(256) void gate_kernel(const unsigned short* __restrict__ zx,
    const float* __restrict__ nw, unsigned short* __restrict__ out)
{
  const int r = blockIdx.x, tid = threadIdx.x;
  __shared__ float red[4];
  const size_t rb = (size_t)r * NPROJ;
  const u16x8_t zv = *(const u16x8_t*)(zx + rb + tid * 8);
  const u16x8_t yv = *(const u16x8_t*)(zx + rb + 2048 + tid * 8);
  float v[8];
#pragma unroll
  for (int i = 0; i < 8; ++i) v[i] = bf2f(yv[i]) * siluf(bf2f(zv[i]));
  float ss = 0.f;
#pragma unroll
  for (int i = 0; i < 8; ++i) ss += v[i] * v[i];
#pragma unroll
  for (int o = 32; o > 0; o >>= 1) ss += __shfl_down(ss, o);
  if ((tid & 63) == 0) red[tid >> 6] = ss;
  __syncthreads();
  const float var = (red[0] + red[1] + red[2] + red[3]) * (1.f / DINNER);
  const float rs = rsqrtf(var + EPSV);
  const float4 w0 = ((const float4*)nw)[tid * 2];
  const float4 w1 = ((const float4*)nw)[tid * 2 + 1];
  u16x8_t o;
  o[0] = f2bf(v[0] * rs * w0.x); o[1] = f2bf(v[1] * rs * w0.y);
  o[2] = f2bf(v[2] * rs * w0.z); o[3] = f2bf(v[3] * rs * w0.w);
  o[4] = f2bf(v[4] * rs * w1.x); o[5] = f2bf(v[5] * rs * w1.y);
  o[6] = f2bf(v[6] * rs * w1.z); o[7] = f2bf(v[7] * rs * w1.w);
  *(u16x8_t*)(out + (size_t)r * DINNER + tid * 8) = o;
}

// ---------------- launch ----------------
extern "C" void kernel_launch(void* const* d_in, const int* in_sizes, int n_in,
                              void* d_out, int out_size, void* d_ws, size_t ws_size,
                              hipStream_t stream) {
  (void)in_sizes; (void)n_in; (void)out_size; (void)ws_size;
  const float* x_in    = (const float*)d_in[0];
  const float* ln_w    = (const float*)d_in[1];
  const float* ln_b    = (const float*)d_in[2];
  const float* in_w    = (const float*)d_in[3];
  const float* conv_w  = (const float*)d_in[4];
  const float* conv_b  = (const float*)d_in[5];
  const float* dt_bias = (const float*)d_in[6];
  const float* A_log   = (const float*)d_in[7];
  const float* Dp      = (const float*)d_in[8];
  const float* norm_w  = (const float*)d_in[9];
  const float* out_w   = (const float*)d_in[10];
  float* xout = (float*)d_out;

  char* ws = (char*)d_ws;
  unsigned short* zxb  = (unsigned short*)ws;                 // 69,730,304
  char* r1 = ws + (size_t)NROWS * NPROJ * 2;
  unsigned short* xn   = (unsigned short*)r1;
  unsigned short* xbcb = (unsigned short*)r1;
  unsigned short* ybf  = (unsigned short*)r1;
  char* wth = r1 + (size_t)NROWS * CONVD * 2;                 // +35,651,584
  unsigned short* inwT = (unsigned short*)wth;
  unsigned short* owT  = (unsigned short*)wth;
  unsigned short* Hbuf = (unsigned short*)wth;                // 16,777,216
  float* cumdec = (float*)(wth + (size_t)SEGS * 128 * 4096 * 2);

  hipMemcpyAsync(xout, x_in, (size_t)NROWS * DMODEL * 4, hipMemcpyDeviceToDevice, stream);

  for (int i = 0; i < 4; ++i) {
    ln_kernel<<<NROWS, 256, 0, stream>>>(xout, ln_w + i * DMODEL, ln_b + i * DMODEL, xn);
    transpose_bf16<<<dim3(133, 32), dim3(32, 32), 0, stream>>>(
        in_w + (size_t)i * DMODEL * NPROJ, inwT, DMODEL, NPROJ);
    gemm_bf16<<<dim3(64, 34), 256, 0, stream>>>(xn, inwT, zxb, NPROJ, DMODEL, NPROJ);
    conv_kernel<<<dim3(2, NROWS / 4), 256, 0, stream>>>(
        zxb, conv_w + (size_t)i * 4 * CONVD, conv_b + i * CONVD, xbcb);
    ssd_chunk_kernel<<<128 * SEGS, 256, 0, stream>>>(xbcb, zxb,
        dt_bias + i * NH, A_log + i * NH, Dp + i * NH,
        zxb + 2048, NPROJ, Hbuf, cumdec);
    scan2_kernel<<<128, 256, 0, stream>>>(Hbuf, cumdec);
    scan3_mfma<<<128 * 15, 256, 0, stream>>>(xbcb, cumdec, Hbuf, zxb + 2048, NPROJ);
    gate_kernel<<<NROWS, 256, 0, stream>>>(zxb, norm_w + i * DINNER, ybf);
    transpose_bf16<<<dim3(32, 64), dim3(32, 32), 0, stream>>>(
        out_w + (size_t)i * DINNER * DMODEL, owT, DINNER, DMODEL);
    gemm_res<<<dim3(64, 8, 2), 256, 0, stream>>>(ybf, owT, xout, DMODEL, DINNER, DMODEL);
  }
}

// Round 19
// 1294.175 us; speedup vs baseline: 1.0490x; 1.0490x over previous
//
#include <hip/hip_runtime.h>
#include <math.h>

#define LSEQ   2048
#define NROWS  8192      // B*L = 4*2048
#define DMODEL 1024
#define DINNER 2048
#define NH     32
#define CONVD  2176
#define NPROJ  4256
#define NPROJ_PAD 4352
#define EPSV   1e-5f
#define SEGS   16
#define TSEG   128       // chunk length

typedef __bf16 bf16x8_t __attribute__((ext_vector_type(8)));
typedef float f32x4_t __attribute__((ext_vector_type(4)));
typedef unsigned short u16x8_t __attribute__((ext_vector_type(8)));

__device__ __forceinline__ unsigned short f2bf(float f) {
  unsigned int u = __float_as_uint(f);
  u += 0x7fffu + ((u >> 16) & 1u);
  return (unsigned short)(u >> 16);
}
__device__ __forceinline__ float bf2f(unsigned short u) {
  return __uint_as_float((unsigned int)u << 16);
}
__device__ __forceinline__ float siluf(float x) { return x / (1.f + expf(-x)); }

// async global->LDS, 16B per lane. LDS dest must be wave-uniform base + lane*16.
__device__ __forceinline__ void gload16(const unsigned short* g, unsigned short* l) {
  __builtin_amdgcn_global_load_lds(
      (const __attribute__((address_space(1))) void*)g,
      (__attribute__((address_space(3))) void*)l, 16, 0, 0);
}

// ---------------- LayerNorm + cast to bf16 ----------------
__global__ __launch_bounds__(256) void ln_kernel(const float* __restrict__ X,
    const float* __restrict__ w, const float* __restrict__ b,
    unsigned short* __restrict__ out)
{
  const int r = blockIdx.x, tid = threadIdx.x;
  __shared__ float red[4];
  const float4 v = ((const float4*)(X + (size_t)r * DMODEL))[tid];
  float s = v.x + v.y + v.z + v.w;
#pragma unroll
  for (int o = 32; o > 0; o >>= 1) s += __shfl_down(s, o);
  if ((tid & 63) == 0) red[tid >> 6] = s;
  __syncthreads();
  const float mu = (red[0] + red[1] + red[2] + red[3]) * (1.f / DMODEL);
  __syncthreads();
  const float dx = v.x - mu, dy = v.y - mu, dz = v.z - mu, dw = v.w - mu;
  float ss = dx * dx + dy * dy + dz * dz + dw * dw;
#pragma unroll
  for (int o = 32; o > 0; o >>= 1) ss += __shfl_down(ss, o);
  if ((tid & 63) == 0) red[tid >> 6] = ss;
  __syncthreads();
  const float var = (red[0] + red[1] + red[2] + red[3]) * (1.f / DMODEL);
  const float rs = rsqrtf(var + EPSV);
  const float4 wv = ((const float4*)w)[tid];
  const float4 bv = ((const float4*)b)[tid];
  const size_t d = (size_t)r * DMODEL + tid * 4;
  out[d + 0] = f2bf(dx * rs * wv.x + bv.x);
  out[d + 1] = f2bf(dy * rs * wv.y + bv.y);
  out[d + 2] = f2bf(dz * rs * wv.z + bv.z);
  out[d + 3] = f2bf(dw * rs * wv.w + bv.w);
}

// ---------------- transpose fp32 (K x N) -> bf16 (N x K) ----------------
__global__ void transpose_bf16(const float* __restrict__ W,
    unsigned short* __restrict__ WT, int K, int N)
{
  __shared__ float t[32][33];
  const int n0 = blockIdx.x * 32, k0 = blockIdx.y * 32;
  const int tx = threadIdx.x, ty = threadIdx.y;
  if (n0 + tx < N) t[ty][tx] = W[(size_t)(k0 + ty) * N + n0 + tx];
  __syncthreads();
  if (n0 + ty < N) WT[(size_t)(n0 + ty) * K + k0 + tx] = f2bf(t[tx][ty]);
}

#define WAITBAR(N) do {                                          \
    __builtin_amdgcn_sched_barrier(0);                           \
    asm volatile("s_waitcnt vmcnt(" #N ")" ::: "memory");        \
    __builtin_amdgcn_s_barrier();                                \
    __builtin_amdgcn_sched_barrier(0);                           \
  } while (0)

#define BAR do {                                 \
    __builtin_amdgcn_sched_barrier(0);           \
    __builtin_amdgcn_s_barrier();                \
    __builtin_amdgcn_sched_barrier(0);           \
  } while (0)

// ---------------- bf16 MFMA GEMM (128x128 tile, 2-deep counted-vmcnt) ----------
// C[M,N] = A[M,K] * BT[N,K]^T. 4 waves (2x2), 4x4 frags/wave. GEMM1 (bf16 out).
#define STAGE(BUF, KT) do {                                        \
    const int kt_ = (KT) * 32;                                     \
    gload16(Ag + kt_,                  sA##BUF + tid * 8);         \
    gload16(Ag + (size_t)64 * K + kt_, sA##BUF + 2048 + tid * 8);  \
    gload16(Bg + kt_,                  sB##BUF + tid * 8);         \
    gload16(Bg + (size_t)64 * K + kt_, sB##BUF + 2048 + tid * 8);  \
  } while (0)

#define COMPUTE(BUF) do {                                                           \
    bf16x8_t af[4], bfr[4];                                                         \
    _Pragma("unroll")                                                               \
    for (int mi = 0; mi < 4; ++mi)                                                  \
      af[mi] = *(const bf16x8_t*)(sA##BUF + (wr * 64 + mi * 16 + la) * 32 + lb * 8);\
    _Pragma("unroll")                                                               \
    for (int ni = 0; ni < 4; ++ni)                                                  \
      bfr[ni] = *(const bf16x8_t*)(sB##BUF + (wc * 64 + ni * 16 + la) * 32 + lb * 8);\
    _Pragma("unroll")                                                               \
    for (int mi = 0; mi < 4; ++mi)                                                  \
      _Pragma("unroll")                                                             \
      for (int ni = 0; ni < 4; ++ni)                                                \
        acc[mi][ni] = __builtin_amdgcn_mfma_f32_16x16x32_bf16(af[mi], bfr[ni],      \
                                                              acc[mi][ni], 0, 0, 0);\
  } while (0)

__global__ __launch_bounds__(256) void gemm_bf16(
    const unsigned short* __restrict__ A,
    const unsigned short* __restrict__ BT,
    unsigned short* __restrict__ Cb,
    int N, int K, int ldc)
{
  __shared__ __attribute__((aligned(16))) unsigned short sA0[128 * 32];
  __shared__ __attribute__((aligned(16))) unsigned short sA1[128 * 32];
  __shared__ __attribute__((aligned(16))) unsigned short sB0[128 * 32];
  __shared__ __attribute__((aligned(16))) unsigned short sB1[128 * 32];
  const int tid = threadIdx.x;
  const int w = tid >> 6, l = tid & 63;
  const int wr = w >> 1, wc = w & 1;
  const int la = l & 15, lb = l >> 4;
  const int m0 = blockIdx.x * 128, n0 = blockIdx.y * 128;
  f32x4_t acc[4][4];
#pragma unroll
  for (int i = 0; i < 4; ++i)
#pragma unroll
    for (int j = 0; j < 4; ++j) acc[i][j] = (f32x4_t){0.f, 0.f, 0.f, 0.f};

  const int r0 = tid >> 2, q0 = tid & 3;
  const unsigned short* Ag = A + (size_t)(m0 + r0) * K + q0 * 8;
  const unsigned short* Bg = BT + (size_t)(n0 + r0) * K + q0 * 8;
  const int nkt = K / 32;

  STAGE(0, 0);
  STAGE(1, 1);

  for (int t = 0; t < nkt - 2; t += 2) {
    WAITBAR(4);
    COMPUTE(0);
    BAR;
    STAGE(0, t + 2);
    WAITBAR(4);
    COMPUTE(1);
    BAR;
    STAGE(1, t + 3);
  }
  WAITBAR(4);
  COMPUTE(0);
  WAITBAR(0);
  COMPUTE(1);

#pragma unroll
  for (int mi = 0; mi < 4; ++mi) {
#pragma unroll
    for (int ni = 0; ni < 4; ++ni) {
      const int col = n0 + wc * 64 + ni * 16 + la;
      if (col < N) {
#pragma unroll
        for (int r = 0; r < 4; ++r) {
          const int row = m0 + wr * 64 + mi * 16 + lb * 4 + r;
          Cb[(size_t)row * ldc + col] = f2bf(acc[mi][ni][r]);
        }
      }
    }
  }
}

// ---------------- GEMM2: fp32 residual accumulate (non-atomic, full K) ----------
__global__ __launch_bounds__(256) void gemm_res(
    const unsigned short* __restrict__ A,
    const unsigned short* __restrict__ BT,
    float* __restrict__ Cf,
    int N, int K, int ldc)
{
  __shared__ __attribute__((aligned(16))) unsigned short sA0[128 * 32];
  __shared__ __attribute__((aligned(16))) unsigned short sA1[128 * 32];
  __shared__ __attribute__((aligned(16))) unsigned short sB0[128 * 32];
  __shared__ __attribute__((aligned(16))) unsigned short sB1[128 * 32];
  const int tid = threadIdx.x;
  const int w = tid >> 6, l = tid & 63;
  const int wr = w >> 1, wc = w & 1;
  const int la = l & 15, lb = l >> 4;
  const int m0 = blockIdx.x * 128, n0 = blockIdx.y * 128;
  f32x4_t acc[4][4];
#pragma unroll
  for (int i = 0; i < 4; ++i)
#pragma unroll
    for (int j = 0; j < 4; ++j) acc[i][j] = (f32x4_t){0.f, 0.f, 0.f, 0.f};

  const int r0 = tid >> 2, q0 = tid & 3;
  const unsigned short* Ag = A + (size_t)(m0 + r0) * K + q0 * 8;
  const unsigned short* Bg = BT + (size_t)(n0 + r0) * K + q0 * 8;
  const int nkt = K / 32;

  STAGE(0, 0);
  STAGE(1, 1);

  for (int t = 0; t < nkt - 2; t += 2) {
    WAITBAR(4);
    COMPUTE(0);
    BAR;
    STAGE(0, t + 2);
    WAITBAR(4);
    COMPUTE(1);
    BAR;
    STAGE(1, t + 3);
  }
  WAITBAR(4);
  COMPUTE(0);
  WAITBAR(0);
  COMPUTE(1);

#pragma unroll
  for (int mi = 0; mi < 4; ++mi) {
#pragma unroll
    for (int ni = 0; ni < 4; ++ni) {
      const int col = n0 + wc * 64 + ni * 16 + la;
      if (col < N) {
#pragma unroll
        for (int r = 0; r < 4; ++r) {
          const int row = m0 + wr * 64 + mi * 16 + lb * 4 + r;
          const size_t idx = (size_t)row * ldc + col;
          Cf[idx] += acc[mi][ni][r];
        }
      }
    }
  }
}

// ---------------- causal depthwise conv (width 4) + silu, 4 rows/block ----------
__global__ __launch_bounds__(256) void conv_kernel(const unsigned short* __restrict__ zx,
    const float* __restrict__ cw, const float* __restrict__ cb,
    unsigned short* __restrict__ out)
{
  const int c8 = (blockIdx.x * 256 + threadIdx.x) * 8;
  if (c8 >= CONVD) return;
  const int r4 = blockIdx.y * 4;           // first output row
  const int l4 = r4 & (LSEQ - 1);          // position within batch
  float vin[7][8];
#pragma unroll
  for (int i = 0; i < 7; ++i) {
    if (l4 - 3 + i >= 0) {
      const u16x8_t v = *(const u16x8_t*)(zx + (size_t)(r4 - 3 + i) * NPROJ + DINNER + c8);
#pragma unroll
      for (int e = 0; e < 8; ++e) vin[i][e] = bf2f(v[e]);
    } else {
#pragma unroll
      for (int e = 0; e < 8; ++e) vin[i][e] = 0.f;
    }
  }
  float wk[4][8], bias[8];
  {
    const float4 b0 = *(const float4*)(cb + c8);
    const float4 b1 = *(const float4*)(cb + c8 + 4);
    bias[0]=b0.x; bias[1]=b0.y; bias[2]=b0.z; bias[3]=b0.w;
    bias[4]=b1.x; bias[5]=b1.y; bias[6]=b1.z; bias[7]=b1.w;
#pragma unroll
    for (int k = 0; k < 4; ++k) {
      const float4 w0 = *(const float4*)(cw + k * CONVD + c8);
      const float4 w1 = *(const float4*)(cw + k * CONVD + c8 + 4);
      wk[k][0]=w0.x; wk[k][1]=w0.y; wk[k][2]=w0.z; wk[k][3]=w0.w;
      wk[k][4]=w1.x; wk[k][5]=w1.y; wk[k][6]=w1.z; wk[k][7]=w1.w;
    }
  }
#pragma unroll
  for (int rr = 0; rr < 4; ++rr) {
    float acc[8];
#pragma unroll
    for (int e = 0; e < 8; ++e) acc[e] = bias[e];
#pragma unroll
    for (int k = 0; k < 4; ++k)
#pragma unroll
      for (int e = 0; e < 8; ++e)
        acc[e] = fmaf(vin[rr + k][e], wk[k][e], acc[e]);
    u16x8_t o;
#pragma unroll
    for (int e = 0; e < 8; ++e) o[e] = f2bf(siluf(acc[e]));
    *(u16x8_t*)(out + (size_t)(r4 + rr) * CONVD + c8) = o;
  }
}

// ---------------- chunked SSD pass A (MFMA): intra-chunk Y + local end-state ----------------
// dt/softplus/log-decay folded in (wave 0). grid = 128 bh * 16 chunks, 256 thr.
// LDS 50KB (3 blocks/CU): Btw overlays CB rows 0..63 after Y1 consumes M.
#define CBB(t, cbyte)  ((char*)CB  + (t) * 256 + ((cbyte) ^ (((t) & 7) << 4)))
#define XTB(p, cbyte)  ((char*)Xt  + (p) * 256 + ((cbyte) ^ (((p) & 7) << 4)))
__global__ __launch_bounds__(256) void ssd_chunk_kernel(
    const unsigned short* __restrict__ xbc,   // NROWS x CONVD (xs | B | C)
    const unsigned short* __restrict__ zraw,  // NROWS x NPROJ (raw proj, dt col 4224+h)
    const float* __restrict__ dt_bias,
    const float* __restrict__ A_log,
    const float* __restrict__ Dp,
    unsigned short* __restrict__ y, int ldy,  // zxb+2048, NPROJ
    unsigned short* __restrict__ H,           // [SEGS][128][4096] (p*64+n)
    float* __restrict__ cumdec)               // [128][LSEQ]
{
  __shared__ unsigned short CB[TSEG * 128];   // C(0:64)|B(64:128) -> M -> Btw   32KB
  __shared__ unsigned short Xt[64 * TSEG];    // X^T [p][t]                      16KB
  __shared__ float cumS[TSEG], dtS[TSEG], wS[TSEG];
  const int id = blockIdx.x;
  const int bh = id >> 4, ch = id & 15;
  const int b = bh >> 5, h = bh & 31;
  const int tid = threadIdx.x;
  const int w = tid >> 6, l = tid & 63;
  const int la = l & 15, lb = l >> 4;
  const size_t row0 = (size_t)b * LSEQ + (size_t)ch * TSEG;
  const unsigned short* xr = xbc + row0 * CONVD;
  const float dp = Dp[h];

  // stage C, B (swizzled rows) and X^T
  {
    const int t = tid >> 1, q = tid & 1;
    const unsigned short* src = xr + (size_t)t * CONVD;
#pragma unroll
    for (int j = 0; j < 4; ++j) {
      const int c0 = q * 32 + j * 8;
      *(u16x8_t*)CBB(t, c0 * 2)       = *(const u16x8_t*)(src + 2112 + c0);  // C
      *(u16x8_t*)CBB(t, 128 + c0 * 2) = *(const u16x8_t*)(src + 2048 + c0);  // B
      const u16x8_t xv = *(const u16x8_t*)(src + h * 64 + c0);
#pragma unroll
      for (int e = 0; e < 8; ++e)
        *(unsigned short*)XTB(c0 + e, t * 2) = xv[e];
    }
  }
  if (w == 0) {  // dt softplus + log-decay + cumulative sums
    const float bias = dt_bias[h];
    const float aexp = __expf(A_log[h]);
    const float x0 = bf2f(zraw[(row0 + l) * NPROJ + (DINNER + CONVD) + h]) + bias;
    const float x1 = bf2f(zraw[(row0 + 64 + l) * NPROJ + (DINNER + CONVD) + h]) + bias;
    const float d0 = (x0 > 20.f) ? x0 : log1pf(__expf(x0));
    const float d1 = (x1 > 20.f) ? x1 : log1pf(__expf(x1));
    float a0 = -d0 * aexp;
    float a1 = -d1 * aexp;
#pragma unroll
    for (int o = 1; o < 64; o <<= 1) { const float u = __shfl_up(a0, o); if (l >= o) a0 += u; }
    const float tot0 = __shfl(a0, 63);
#pragma unroll
    for (int o = 1; o < 64; o <<= 1) { const float u = __shfl_up(a1, o); if (l >= o) a1 += u; }
    a1 += tot0;
    const float cT = __shfl(a1, 63);
    cumS[l] = a0;       cumS[64 + l] = a1;
    dtS[l] = d0;        dtS[64 + l] = d1;
    wS[l] = __expf(cT - a0) * d0;
    wS[64 + l] = __expf(cT - a1) * d1;
    float* cdg = cumdec + (size_t)bh * LSEQ + (size_t)ch * TSEG;
    cdg[l] = __expf(a0);
    cdg[64 + l] = __expf(a1);
  }
  __syncthreads();

  // G = C @ B^T : wave w owns rows [w*32, w*32+32)
  f32x4_t g[2][8];
#pragma unroll
  for (int mi = 0; mi < 2; ++mi)
#pragma unroll
    for (int ni = 0; ni < 8; ++ni) g[mi][ni] = (f32x4_t){0.f, 0.f, 0.f, 0.f};
#pragma unroll
  for (int ks = 0; ks < 2; ++ks) {
    bf16x8_t af[2], bfr[8];
#pragma unroll
    for (int mi = 0; mi < 2; ++mi)
      af[mi] = *(const bf16x8_t*)CBB(w * 32 + mi * 16 + la, ks * 64 + lb * 16);
#pragma unroll
    for (int ni = 0; ni < 8; ++ni)
      bfr[ni] = *(const bf16x8_t*)CBB(ni * 16 + la, 128 + ks * 64 + lb * 16);
#pragma unroll
    for (int mi = 0; mi < 2; ++mi)
#pragma unroll
      for (int ni = 0; ni < 8; ++ni)
        g[mi][ni] = __builtin_amdgcn_mfma_f32_16x16x32_bf16(af[mi], bfr[ni], g[mi][ni], 0, 0, 0);
  }
  __syncthreads();   // all CB reads done before M overwrites it

  // mask -> M (overwrites CB)
#pragma unroll
  for (int mi = 0; mi < 2; ++mi) {
#pragma unroll
    for (int ni = 0; ni < 8; ++ni) {
      const int s = ni * 16 + la;
#pragma unroll
      for (int r = 0; r < 4; ++r) {
        const int t = w * 32 + mi * 16 + lb * 4 + r;
        float mv = 0.f;
        if (s <= t) mv = g[mi][ni][r] * __expf(cumS[t] - cumS[s]) * dtS[s];
        if (s == t) mv += dp;
        *(unsigned short*)CBB(t, s * 2) = f2bf(mv);
      }
    }
  }
  __syncthreads();   // M visible to all waves

  // Y1 = M @ X : K = 128
  f32x4_t y1[2][4];
#pragma unroll
  for (int mi = 0; mi < 2; ++mi)
#pragma unroll
    for (int ni = 0; ni < 4; ++ni) y1[mi][ni] = (f32x4_t){0.f, 0.f, 0.f, 0.f};
#pragma unroll
  for (int ks = 0; ks < 4; ++ks) {
    bf16x8_t af[2], xf[4];
#pragma unroll
    for (int mi = 0; mi < 2; ++mi)
      af[mi] = *(const bf16x8_t*)CBB(w * 32 + mi * 16 + la, ks * 64 + lb * 16);
#pragma unroll
    for (int ni = 0; ni < 4; ++ni)
      xf[ni] = *(const bf16x8_t*)XTB(ni * 16 + la, ks * 64 + lb * 16);
#pragma unroll
    for (int mi = 0; mi < 2; ++mi)
#pragma unroll
      for (int ni = 0; ni < 4; ++ni)
        y1[mi][ni] = __builtin_amdgcn_mfma_f32_16x16x32_bf16(af[mi], xf[ni], y1[mi][ni], 0, 0, 0);
  }
  // write y while M region is being recycled
  unsigned short* yg = y + row0 * ldy + h * 64;
#pragma unroll
  for (int mi = 0; mi < 2; ++mi)
#pragma unroll
    for (int ni = 0; ni < 4; ++ni)
#pragma unroll
      for (int r = 0; r < 4; ++r) {
        const int t = w * 32 + mi * 16 + lb * 4 + r;
        yg[(size_t)t * ldy + ni * 16 + la] = f2bf(y1[mi][ni][r]);
      }
  __syncthreads();   // Y1 done reading CB (M dead)

  // Btw = (w_s * B)^T into CB rows 0..63 (global re-read, L2-hot)
  {
    const int s = tid >> 1, q = tid & 1;
    const unsigned short* src = xr + (size_t)s * CONVD + 2048;
    const float ww = wS[s];
#pragma unroll
    for (int j = 0; j < 4; ++j) {
      const int c0 = q * 32 + j * 8;
      const u16x8_t bv = *(const u16x8_t*)(src + c0);
#pragma unroll
      for (int e = 0; e < 8; ++e)
        *(unsigned short*)CBB(c0 + e, s * 2) = f2bf(bf2f(bv[e]) * ww);
    }
  }
  __syncthreads();   // Btw visible

  // Hloc = X^T @ Btw^T : K = 128
  f32x4_t hacc[4];
#pragma unroll
  for (int ni = 0; ni < 4; ++ni) hacc[ni] = (f32x4_t){0.f, 0.f, 0.f, 0.f};
#pragma unroll
  for (int ks = 0; ks < 4; ++ks) {
    const bf16x8_t af = *(const bf16x8_t*)XTB(w * 16 + la, ks * 64 + lb * 16);
    bf16x8_t bw[4];
#pragma unroll
    for (int ni = 0; ni < 4; ++ni)
      bw[ni] = *(const bf16x8_t*)CBB(ni * 16 + la, ks * 64 + lb * 16);
#pragma unroll
    for (int ni = 0; ni < 4; ++ni)
      hacc[ni] = __builtin_amdgcn_mfma_f32_16x16x32_bf16(af, bw[ni], hacc[ni], 0, 0, 0);
  }

  unsigned short* Hg = H + ((size_t)ch * 128 + bh) * 4096;
#pragma unroll
  for (int ni = 0; ni < 4; ++ni)
#pragma unroll
    for (int r = 0; r < 4; ++r) {
      const int p = w * 16 + lb * 4 + r;
      Hg[p * 64 + ni * 16 + la] = f2bf(hacc[ni][r]);
    }
}

// ---------------- scan pass 2: segment-summary scan (end-state -> start-state) ----------------
__global__ __launch_bounds__(256) void scan2_kernel(
    unsigned short* __restrict__ H, const float* __restrict__ cumdec)
{
  const int bh = blockIdx.x;
  const int e = threadIdx.x * 16;
  float hs[16];
#pragma unroll
  for (int k = 0; k < 16; ++k) hs[k] = 0.f;
  unsigned short* Hb = H + (size_t)bh * 4096 + e;
  const float* cd = cumdec + (size_t)bh * LSEQ;
  for (int s = 0; s < SEGS; ++s) {
    unsigned short* p = Hb + (size_t)s * 128 * 4096;
    const float rseg = cd[s * TSEG + TSEG - 1];
    u16x8_t v0 = *(u16x8_t*)p, v1 = *(u16x8_t*)(p + 8);
    u16x8_t w0, w1;
#pragma unroll
    for (int k = 0; k < 8; ++k) {
      const float tmp = bf2f(v0[k]);
      w0[k] = f2bf(hs[k]);
      hs[k] = fmaf(rseg, hs[k], tmp);
    }
#pragma unroll
    for (int k = 0; k < 8; ++k) {
      const float tmp = bf2f(v1[k]);
      w1[k] = f2bf(hs[k + 8]);
      hs[k + 8] = fmaf(rseg, hs[k + 8], tmp);
    }
    *(u16x8_t*)p = w0;
    *(u16x8_t*)(p + 8) = w1;
  }
}

// ---------------- scan pass 3 (MFMA): Y += diag(cumdec) * C @ Hstart^T ----------------
#define CSB(t, cbyte) ((char*)Cs + (t) * 128 + ((cbyte) ^ (((t) & 7) << 4)))
#define HSB(p, cbyte) ((char*)Hs + (p) * 128 + ((cbyte) ^ (((p) & 7) << 4)))
__global__ __launch_bounds__(256) void scan3_mfma(
    const unsigned short* __restrict__ xbc,
    const float* __restrict__ cumdec,
    const unsigned short* __restrict__ H,
    unsigned short* __restrict__ y, int ldy)
{
  __shared__ unsigned short Cs[TSEG * 64];  // 16KB
  __shared__ unsigned short Hs[64 * 64];    // 8KB
  __shared__ float cdS[TSEG];
  const int id = blockIdx.x;
  const int bh = id / 15, ch = id % 15 + 1;
  const int b = bh >> 5, h = bh & 31;
  const int tid = threadIdx.x, w = tid >> 6, l = tid & 63;
  const int la = l & 15, lb = l >> 4;
  const size_t row0 = (size_t)b * LSEQ + (size_t)ch * TSEG;
  const unsigned short* xr = xbc + row0 * CONVD;
  {
    const int t = tid >> 1, q = tid & 1;
#pragma unroll
    for (int j = 0; j < 4; ++j) {
      const int c0 = q * 32 + j * 8;
      *(u16x8_t*)CSB(t, c0 * 2) = *(const u16x8_t*)(xr + (size_t)t * CONVD + 2112 + c0);
    }
  }
  {
    const int p = tid >> 2, q = tid & 3;
    const unsigned short* hsrc = H + ((size_t)ch * 128 + bh) * 4096 + p * 64;
#pragma unroll
    for (int j = 0; j < 2; ++j) {
      const int c0 = q * 16 + j * 8;
      *(u16x8_t*)HSB(p, c0 * 2) = *(const u16x8_t*)(hsrc + c0);
    }
  }
  if (tid < TSEG) cdS[tid] = cumdec[(size_t)bh * LSEQ + (size_t)ch * TSEG + tid];
  __syncthreads();
  f32x4_t acc[2][4];
#pragma unroll
  for (int mi = 0; mi < 2; ++mi)
#pragma unroll
    for (int ni = 0; ni < 4; ++ni) acc[mi][ni] = (f32x4_t){0.f, 0.f, 0.f, 0.f};
#pragma unroll
  for (int ks = 0; ks < 2; ++ks) {
    bf16x8_t af[2], bfr[4];
#pragma unroll
    for (int mi = 0; mi < 2; ++mi)
      af[mi] = *(const bf16x8_t*)CSB(w * 32 + mi * 16 + la, ks * 64 + lb * 16);
#pragma unroll
    for (int ni = 0; ni < 4; ++ni)
      bfr[ni] = *(const bf16x8_t*)HSB(ni * 16 + la, ks * 64 + lb * 16);
#pragma unroll
    for (int mi = 0; mi < 2; ++mi)
#pragma unroll
      for (int ni = 0; ni < 4; ++ni)
        acc[mi][ni] = __builtin_amdgcn_mfma_f32_16x16x32_bf16(af[mi], bfr[ni], acc[mi][ni], 0, 0, 0);
  }
  unsigned short* yg = y + row0 * ldy + h * 64;
#pragma unroll
  for (int mi = 0; mi < 2; ++mi)
#pragma unroll
    for (int ni = 0; ni < 4; ++ni)
#pragma unroll
      for (int r = 0; r < 4; ++r) {
        const int t = w * 32 + mi * 16 + lb * 4 + r;
        unsigned short* yp = yg + (size_t)t * ldy + ni * 16 + la;
        *yp = f2bf(bf2f(*yp) + acc[mi][ni][r] * cdS[t]);
      }
}

// ---------------- y * silu(z), RMSNorm, * norm_w -> bf16 ----------------
__global__ __launch_bounds__(256) void gate_kernel(const unsigned short* __restrict__ zx,
    const float* __restrict__ nw, unsigned short* __restrict__ out)
{
  const int r = blockIdx.x, tid = threadIdx.x;
  __shared__ float red[4];
  const size_t rb = (size_t)r * NPROJ;
  const u16x8_t zv = *(const u16x8_t*)(zx + rb + tid * 8);
  const u16x8_t yv = *(const u16x8_t*)(zx + rb + 2048 + tid * 8);
  float v[8];
#pragma unroll
  for (int i = 0; i < 8; ++i) v[i] = bf2f(yv[i]) * siluf(bf2f(zv[i]));
  float ss = 0.f;
#pragma unroll
  for (int i = 0; i < 8; ++i) ss += v[i] * v[i];
#pragma unroll
  for (int o = 32; o > 0; o >>= 1) ss += __shfl_down(ss, o);
  if ((tid & 63) == 0) red[tid >> 6] = ss;
  __syncthreads();
  const float var = (red[0] + red[1] + red[2] + red[3]) * (1.f / DINNER);
  const float rs = rsqrtf(var + EPSV);
  const float4 w0 = ((const float4*)nw)[tid * 2];
  const float4 w1 = ((const float4*)nw)[tid * 2 + 1];
  u16x8_t o;
  o[0] = f2bf(v[0] * rs * w0.x); o[1] = f2bf(v[1] * rs * w0.y);
  o[2] = f2bf(v[2] * rs * w0.z); o[3] = f2bf(v[3] * rs * w0.w);
  o[4] = f2bf(v[4] * rs * w1.x); o[5] = f2bf(v[5] * rs * w1.y);
  o[6] = f2bf(v[6] * rs * w1.z); o[7] = f2bf(v[7] * rs * w1.w);
  *(u16x8_t*)(out + (size_t)r * DINNER + tid * 8) = o;
}

// ---------------- launch ----------------
extern "C" void kernel_launch(void* const* d_in, const int* in_sizes, int n_in,
                              void* d_out, int out_size, void* d_ws, size_t ws_size,
                              hipStream_t stream) {
  (void)in_sizes; (void)n_in; (void)out_size; (void)ws_size;
  const float* x_in    = (const float*)d_in[0];
  const float* ln_w    = (const float*)d_in[1];
  const float* ln_b    = (const float*)d_in[2];
  const float* in_w    = (const float*)d_in[3];
  const float* conv_w  = (const float*)d_in[4];
  const float* conv_b  = (const float*)d_in[5];
  const float* dt_bias = (const float*)d_in[6];
  const float* A_log   = (const float*)d_in[7];
  const float* Dp      = (const float*)d_in[8];
  const float* norm_w  = (const float*)d_in[9];
  const float* out_w   = (const float*)d_in[10];
  float* xout = (float*)d_out;

  char* ws = (char*)d_ws;
  unsigned short* zxb  = (unsigned short*)ws;                 // 69,730,304
  char* r1 = ws + (size_t)NROWS * NPROJ * 2;
  unsigned short* xn   = (unsigned short*)r1;
  unsigned short* xbcb = (unsigned short*)r1;
  unsigned short* ybf  = (unsigned short*)r1;
  char* wth = r1 + (size_t)NROWS * CONVD * 2;                 // +35,651,584
  unsigned short* inwT = (unsigned short*)wth;
  unsigned short* owT  = (unsigned short*)wth;
  unsigned short* Hbuf = (unsigned short*)wth;                // 16,777,216
  float* cumdec = (float*)(wth + (size_t)SEGS * 128 * 4096 * 2);

  hipMemcpyAsync(xout, x_in, (size_t)NROWS * DMODEL * 4, hipMemcpyDeviceToDevice, stream);

  for (int i = 0; i < 4; ++i) {
    ln_kernel<<<NROWS, 256, 0, stream>>>(xout, ln_w + i * DMODEL, ln_b + i * DMODEL, xn);
    transpose_bf16<<<dim3(133, 32), dim3(32, 32), 0, stream>>>(
        in_w + (size_t)i * DMODEL * NPROJ, inwT, DMODEL, NPROJ);
    gemm_bf16<<<dim3(64, 34), 256, 0, stream>>>(xn, inwT, zxb, NPROJ, DMODEL, NPROJ);
    conv_kernel<<<dim3(2, NROWS / 4), 256, 0, stream>>>(
        zxb, conv_w + (size_t)i * 4 * CONVD, conv_b + i * CONVD, xbcb);
    ssd_chunk_kernel<<<128 * SEGS, 256, 0, stream>>>(xbcb, zxb,
        dt_bias + i * NH, A_log + i * NH, Dp + i * NH,
        zxb + 2048, NPROJ, Hbuf, cumdec);
    scan2_kernel<<<128, 256, 0, stream>>>(Hbuf, cumdec);
    scan3_mfma<<<128 * 15, 256, 0, stream>>>(xbcb, cumdec, Hbuf, zxb + 2048, NPROJ);
    gate_kernel<<<NROWS, 256, 0, stream>>>(zxb, norm_w + i * DINNER, ybf);
    transpose_bf16<<<dim3(32, 64), dim3(32, 32), 0, stream>>>(
        out_w + (size_t)i * DINNER * DMODEL, owT, DINNER, DMODEL);
    gemm_res<<<dim3(64, 8), 256, 0, stream>>>(ybf, owT, xout, DMODEL, DINNER, DMODEL);
  }
}

// Round 20
// 1292.429 us; speedup vs baseline: 1.0504x; 1.0014x over previous
//
#include <hip/hip_runtime.h>
#include <math.h>

#define LSEQ   2048
#define NROWS  8192      // B*L = 4*2048
#define DMODEL 1024
#define DINNER 2048
#define NH     32
#define CONVD  2176
#define NPROJ  4256
#define NPROJ_PAD 4352
#define EPSV   1e-5f
#define SEGS   16
#define TSEG   128       // chunk length

typedef __bf16 bf16x8_t __attribute__((ext_vector_type(8)));
typedef float f32x4_t __attribute__((ext_vector_type(4)));
typedef unsigned short u16x8_t __attribute__((ext_vector_type(8)));
typedef unsigned short u16x4_t __attribute__((ext_vector_type(4)));

__device__ __forceinline__ unsigned short f2bf(float f) {
  unsigned int u = __float_as_uint(f);
  u += 0x7fffu + ((u >> 16) & 1u);
  return (unsigned short)(u >> 16);
}
__device__ __forceinline__ float bf2f(unsigned short u) {
  return __uint_as_float((unsigned int)u << 16);
}
__device__ __forceinline__ float siluf(float x) { return x / (1.f + expf(-x)); }
__device__ __forceinline__ float wave_sum(float s) {
#pragma unroll
  for (int o = 1; o < 64; o <<= 1) s += __shfl_xor(s, o);
  return s;
}

// async global->LDS, 16B per lane. LDS dest must be wave-uniform base + lane*16.
__device__ __forceinline__ void gload16(const unsigned short* g, unsigned short* l) {
  __builtin_amdgcn_global_load_lds(
      (const __attribute__((address_space(1))) void*)g,
      (__attribute__((address_space(3))) void*)l, 16, 0, 0);
}

// ---------------- LayerNorm + cast to bf16 (wave-per-row, 4 rows/block) ---------
__global__ __launch_bounds__(256) void ln_kernel(const float* __restrict__ X,
    const float* __restrict__ w, const float* __restrict__ b,
    unsigned short* __restrict__ out)
{
  const int r = blockIdx.x * 4 + (threadIdx.x >> 6);
  const int l = threadIdx.x & 63;
  const float4* xr = (const float4*)(X + (size_t)r * DMODEL);
  float4 v[4];
#pragma unroll
  for (int j = 0; j < 4; ++j) v[j] = xr[l + 64 * j];
  float s = 0.f;
#pragma unroll
  for (int j = 0; j < 4; ++j) s += v[j].x + v[j].y + v[j].z + v[j].w;
  const float mu = wave_sum(s) * (1.f / DMODEL);
  float ss = 0.f;
#pragma unroll
  for (int j = 0; j < 4; ++j) {
    v[j].x -= mu; v[j].y -= mu; v[j].z -= mu; v[j].w -= mu;
    ss += v[j].x * v[j].x + v[j].y * v[j].y + v[j].z * v[j].z + v[j].w * v[j].w;
  }
  const float rs = rsqrtf(wave_sum(ss) * (1.f / DMODEL) + EPSV);
#pragma unroll
  for (int j = 0; j < 4; ++j) {
    const float4 wv = ((const float4*)w)[l + 64 * j];
    const float4 bv = ((const float4*)b)[l + 64 * j];
    u16x4_t o;
    o[0] = f2bf(v[j].x * rs * wv.x + bv.x);
    o[1] = f2bf(v[j].y * rs * wv.y + bv.y);
    o[2] = f2bf(v[j].z * rs * wv.z + bv.z);
    o[3] = f2bf(v[j].w * rs * wv.w + bv.w);
    *(u16x4_t*)(out + (size_t)r * DMODEL + (l + 64 * j) * 4) = o;
  }
}

// ---------------- transpose fp32 (K x N) -> bf16 (N x K) ----------------
__global__ void transpose_bf16(const float* __restrict__ W,
    unsigned short* __restrict__ WT, int K, int N)
{
  __shared__ float t[32][33];
  const int n0 = blockIdx.x * 32, k0 = blockIdx.y * 32;
  const int tx = threadIdx.x, ty = threadIdx.y;
  if (n0 + tx < N) t[ty][tx] = W[(size_t)(k0 + ty) * N + n0 + tx];
  __syncthreads();
  if (n0 + ty < N) WT[(size_t)(n0 + ty) * K + k0 + tx] = f2bf(t[tx][ty]);
}

#define WAITBAR(N) do {                                          \
    __builtin_amdgcn_sched_barrier(0);                           \
    asm volatile("s_waitcnt vmcnt(" #N ")" ::: "memory");        \
    __builtin_amdgcn_s_barrier();                                \
    __builtin_amdgcn_sched_barrier(0);                           \
  } while (0)

#define BAR do {                                 \
    __builtin_amdgcn_sched_barrier(0);           \
    __builtin_amdgcn_s_barrier();                \
    __builtin_amdgcn_sched_barrier(0);           \
  } while (0)

// ---------------- bf16 MFMA GEMM (128x128 tile, 2-deep counted-vmcnt) ----------
// C[M,N] = A[M,K] * BT[N,K]^T. 4 waves (2x2), 4x4 frags/wave. GEMM1 (bf16 out).
#define STAGE(BUF, KT) do {                                        \
    const int kt_ = (KT) * 32;                                     \
    gload16(Ag + kt_,                  sA##BUF + tid * 8);         \
    gload16(Ag + (size_t)64 * K + kt_, sA##BUF + 2048 + tid * 8);  \
    gload16(Bg + kt_,                  sB##BUF + tid * 8);         \
    gload16(Bg + (size_t)64 * K + kt_, sB##BUF + 2048 + tid * 8);  \
  } while (0)

#define COMPUTE(BUF) do {                                                           \
    bf16x8_t af[4], bfr[4];                                                         \
    _Pragma("unroll")                                                               \
    for (int mi = 0; mi < 4; ++mi)                                                  \
      af[mi] = *(const bf16x8_t*)(sA##BUF + (wr * 64 + mi * 16 + la) * 32 + lb * 8);\
    _Pragma("unroll")                                                               \
    for (int ni = 0; ni < 4; ++ni)                                                  \
      bfr[ni] = *(const bf16x8_t*)(sB##BUF + (wc * 64 + ni * 16 + la) * 32 + lb * 8);\
    _Pragma("unroll")                                                               \
    for (int mi = 0; mi < 4; ++mi)                                                  \
      _Pragma("unroll")                                                             \
      for (int ni = 0; ni < 4; ++ni)                                                \
        acc[mi][ni] = __builtin_amdgcn_mfma_f32_16x16x32_bf16(af[mi], bfr[ni],      \
                                                              acc[mi][ni], 0, 0, 0);\
  } while (0)

__global__ __launch_bounds__(256) void gemm_bf16(
    const unsigned short* __restrict__ A,
    const unsigned short* __restrict__ BT,
    unsigned short* __restrict__ Cb,
    int N, int K, int ldc)
{
  __shared__ __attribute__((aligned(16))) unsigned short sA0[128 * 32];
  __shared__ __attribute__((aligned(16))) unsigned short sA1[128 * 32];
  __shared__ __attribute__((aligned(16))) unsigned short sB0[128 * 32];
  __shared__ __attribute__((aligned(16))) unsigned short sB1[128 * 32];
  const int tid = threadIdx.x;
  const int w = tid >> 6, l = tid & 63;
  const int wr = w >> 1, wc = w & 1;
  const int la = l & 15, lb = l >> 4;
  const int m0 = blockIdx.x * 128, n0 = blockIdx.y * 128;
  f32x4_t acc[4][4];
#pragma unroll
  for (int i = 0; i < 4; ++i)
#pragma unroll
    for (int j = 0; j < 4; ++j) acc[i][j] = (f32x4_t){0.f, 0.f, 0.f, 0.f};

  const int r0 = tid >> 2, q0 = tid & 3;
  const unsigned short* Ag = A + (size_t)(m0 + r0) * K + q0 * 8;
  const unsigned short* Bg = BT + (size_t)(n0 + r0) * K + q0 * 8;
  const int nkt = K / 32;

  STAGE(0, 0);
  STAGE(1, 1);

  for (int t = 0; t < nkt - 2; t += 2) {
    WAITBAR(4);
    COMPUTE(0);
    BAR;
    STAGE(0, t + 2);
    WAITBAR(4);
    COMPUTE(1);
    BAR;
    STAGE(1, t + 3);
  }
  WAITBAR(4);
  COMPUTE(0);
  WAITBAR(0);
  COMPUTE(1);

#pragma unroll
  for (int mi = 0; mi < 4; ++mi) {
#pragma unroll
    for (int ni = 0; ni < 4; ++ni) {
      const int col = n0 + wc * 64 + ni * 16 + la;
      if (col < N) {
#pragma unroll
        for (int r = 0; r < 4; ++r) {
          const int row = m0 + wr * 64 + mi * 16 + lb * 4 + r;
          Cb[(size_t)row * ldc + col] = f2bf(acc[mi][ni][r]);
        }
      }
    }
  }
}

// ---------------- GEMM2: fp32 residual accumulate (non-atomic, full K) ----------
__global__ __launch_bounds__(256) void gemm_res(
    const unsigned short* __restrict__ A,
    const unsigned short* __restrict__ BT,
    float* __restrict__ Cf,
    int N, int K, int ldc)
{
  __shared__ __attribute__((aligned(16))) unsigned short sA0[128 * 32];
  __shared__ __attribute__((aligned(16))) unsigned short sA1[128 * 32];
  __shared__ __attribute__((aligned(16))) unsigned short sB0[128 * 32];
  __shared__ __attribute__((aligned(16))) unsigned short sB1[128 * 32];
  const int tid = threadIdx.x;
  const int w = tid >> 6, l = tid & 63;
  const int wr = w >> 1, wc = w & 1;
  const int la = l & 15, lb = l >> 4;
  const int m0 = blockIdx.x * 128, n0 = blockIdx.y * 128;
  f32x4_t acc[4][4];
#pragma unroll
  for (int i = 0; i < 4; ++i)
#pragma unroll
    for (int j = 0; j < 4; ++j) acc[i][j] = (f32x4_t){0.f, 0.f, 0.f, 0.f};

  const int r0 = tid >> 2, q0 = tid & 3;
  const unsigned short* Ag = A + (size_t)(m0 + r0) * K + q0 * 8;
  const unsigned short* Bg = BT + (size_t)(n0 + r0) * K + q0 * 8;
  const int nkt = K / 32;

  STAGE(0, 0);
  STAGE(1, 1);

  for (int t = 0; t < nkt - 2; t += 2) {
    WAITBAR(4);
    COMPUTE(0);
    BAR;
    STAGE(0, t + 2);
    WAITBAR(4);
    COMPUTE(1);
    BAR;
    STAGE(1, t + 3);
  }
  WAITBAR(4);
  COMPUTE(0);
  WAITBAR(0);
  COMPUTE(1);

#pragma unroll
  for (int mi = 0; mi < 4; ++mi) {
#pragma unroll
    for (int ni = 0; ni < 4; ++ni) {
      const int col = n0 + wc * 64 + ni * 16 + la;
      if (col < N) {
#pragma unroll
        for (int r = 0; r < 4; ++r) {
          const int row = m0 + wr * 64 + mi * 16 + lb * 4 + r;
          const size_t idx = (size_t)row * ldc + col;
          Cf[idx] += acc[mi][ni][r];
        }
      }
    }
  }
}

// ---------------- causal depthwise conv (width 4) + silu, 4 rows/block ----------
__global__ __launch_bounds__(256) void conv_kernel(const unsigned short* __restrict__ zx,
    const float* __restrict__ cw, const float* __restrict__ cb,
    unsigned short* __restrict__ out)
{
  const int c8 = (blockIdx.x * 256 + threadIdx.x) * 8;
  if (c8 >= CONVD) return;
  const int r4 = blockIdx.y * 4;           // first output row
  const int l4 = r4 & (LSEQ - 1);          // position within batch
  float vin[7][8];
#pragma unroll
  for (int i = 0; i < 7; ++i) {
    if (l4 - 3 + i >= 0) {
      const u16x8_t v = *(const u16x8_t*)(zx + (size_t)(r4 - 3 + i) * NPROJ + DINNER + c8);
#pragma unroll
      for (int e = 0; e < 8; ++e) vin[i][e] = bf2f(v[e]);
    } else {
#pragma unroll
      for (int e = 0; e < 8; ++e) vin[i][e] = 0.f;
    }
  }
  float wk[4][8], bias[8];
  {
    const float4 b0 = *(const float4*)(cb + c8);
    const float4 b1 = *(const float4*)(cb + c8 + 4);
    bias[0]=b0.x; bias[1]=b0.y; bias[2]=b0.z; bias[3]=b0.w;
    bias[4]=b1.x; bias[5]=b1.y; bias[6]=b1.z; bias[7]=b1.w;
#pragma unroll
    for (int k = 0; k < 4; ++k) {
      const float4 w0 = *(const float4*)(cw + k * CONVD + c8);
      const float4 w1 = *(const float4*)(cw + k * CONVD + c8 + 4);
      wk[k][0]=w0.x; wk[k][1]=w0.y; wk[k][2]=w0.z; wk[k][3]=w0.w;
      wk[k][4]=w1.x; wk[k][5]=w1.y; wk[k][6]=w1.z; wk[k][7]=w1.w;
    }
  }
#pragma unroll
  for (int rr = 0; rr < 4; ++rr) {
    float acc[8];
#pragma unroll
    for (int e = 0; e < 8; ++e) acc[e] = bias[e];
#pragma unroll
    for (int k = 0; k < 4; ++k)
#pragma unroll
      for (int e = 0; e < 8; ++e)
        acc[e] = fmaf(vin[rr + k][e], wk[k][e], acc[e]);
    u16x8_t o;
#pragma unroll
    for (int e = 0; e < 8; ++e) o[e] = f2bf(siluf(acc[e]));
    *(u16x8_t*)(out + (size_t)(r4 + rr) * CONVD + c8) = o;
  }
}

// ---------------- chunked SSD pass A (MFMA): intra-chunk Y + local end-state ----------------
// dt/softplus/log-decay folded in (wave 0). grid = 128 bh * 16 chunks, 256 thr.
// LDS 50KB (3 blocks/CU): Btw overlays CB rows 0..63 after Y1 consumes M.
#define CBB(t, cbyte)  ((char*)CB  + (t) * 256 + ((cbyte) ^ (((t) & 7) << 4)))
#define XTB(p, cbyte)  ((char*)Xt  + (p) * 256 + ((cbyte) ^ (((p) & 7) << 4)))
__global__ __launch_bounds__(256) void ssd_chunk_kernel(
    const unsigned short* __restrict__ xbc,   // NROWS x CONVD (xs | B | C)
    const unsigned short* __restrict__ zraw,  // NROWS x NPROJ (raw proj, dt col 4224+h)
    const float* __restrict__ dt_bias,
    const float* __restrict__ A_log,
    const float* __restrict__ Dp,
    unsigned short* __restrict__ y, int ldy,  // zxb+2048, NPROJ
    unsigned short* __restrict__ H,           // [SEGS][128][4096] (p*64+n)
    float* __restrict__ cumdec)               // [128][LSEQ]
{
  __shared__ unsigned short CB[TSEG * 128];   // C(0:64)|B(64:128) -> M -> Btw   32KB
  __shared__ unsigned short Xt[64 * TSEG];    // X^T [p][t]                      16KB
  __shared__ float cumS[TSEG], dtS[TSEG], wS[TSEG];
  const int id = blockIdx.x;
  const int bh = id >> 4, ch = id & 15;
  const int b = bh >> 5, h = bh & 31;
  const int tid = threadIdx.x;
  const int w = tid >> 6, l = tid & 63;
  const int la = l & 15, lb = l >> 4;
  const size_t row0 = (size_t)b * LSEQ + (size_t)ch * TSEG;
  const unsigned short* xr = xbc + row0 * CONVD;
  const float dp = Dp[h];

  // stage C, B (swizzled rows) and X^T
  {
    const int t = tid >> 1, q = tid & 1;
    const unsigned short* src = xr + (size_t)t * CONVD;
#pragma unroll
    for (int j = 0; j < 4; ++j) {
      const int c0 = q * 32 + j * 8;
      *(u16x8_t*)CBB(t, c0 * 2)       = *(const u16x8_t*)(src + 2112 + c0);  // C
      *(u16x8_t*)CBB(t, 128 + c0 * 2) = *(const u16x8_t*)(src + 2048 + c0);  // B
      const u16x8_t xv = *(const u16x8_t*)(src + h * 64 + c0);
#pragma unroll
      for (int e = 0; e < 8; ++e)
        *(unsigned short*)XTB(c0 + e, t * 2) = xv[e];
    }
  }
  if (w == 0) {  // dt softplus + log-decay + cumulative sums
    const float bias = dt_bias[h];
    const float aexp = __expf(A_log[h]);
    const float x0 = bf2f(zraw[(row0 + l) * NPROJ + (DINNER + CONVD) + h]) + bias;
    const float x1 = bf2f(zraw[(row0 + 64 + l) * NPROJ + (DINNER + CONVD) + h]) + bias;
    const float d0 = (x0 > 20.f) ? x0 : log1pf(__expf(x0));
    const float d1 = (x1 > 20.f) ? x1 : log1pf(__expf(x1));
    float a0 = -d0 * aexp;
    float a1 = -d1 * aexp;
#pragma unroll
    for (int o = 1; o < 64; o <<= 1) { const float u = __shfl_up(a0, o); if (l >= o) a0 += u; }
    const float tot0 = __shfl(a0, 63);
#pragma unroll
    for (int o = 1; o < 64; o <<= 1) { const float u = __shfl_up(a1, o); if (l >= o) a1 += u; }
    a1 += tot0;
    const float cT = __shfl(a1, 63);
    cumS[l] = a0;       cumS[64 + l] = a1;
    dtS[l] = d0;        dtS[64 + l] = d1;
    wS[l] = __expf(cT - a0) * d0;
    wS[64 + l] = __expf(cT - a1) * d1;
    float* cdg = cumdec + (size_t)bh * LSEQ + (size_t)ch * TSEG;
    cdg[l] = __expf(a0);
    cdg[64 + l] = __expf(a1);
  }
  __syncthreads();

  // G = C @ B^T : wave w owns rows [w*32, w*32+32)
  f32x4_t g[2][8];
#pragma unroll
  for (int mi = 0; mi < 2; ++mi)
#pragma unroll
    for (int ni = 0; ni < 8; ++ni) g[mi][ni] = (f32x4_t){0.f, 0.f, 0.f, 0.f};
#pragma unroll
  for (int ks = 0; ks < 2; ++ks) {
    bf16x8_t af[2], bfr[8];
#pragma unroll
    for (int mi = 0; mi < 2; ++mi)
      af[mi] = *(const bf16x8_t*)CBB(w * 32 + mi * 16 + la, ks * 64 + lb * 16);
#pragma unroll
    for (int ni = 0; ni < 8; ++ni)
      bfr[ni] = *(const bf16x8_t*)CBB(ni * 16 + la, 128 + ks * 64 + lb * 16);
#pragma unroll
    for (int mi = 0; mi < 2; ++mi)
#pragma unroll
      for (int ni = 0; ni < 8; ++ni)
        g[mi][ni] = __builtin_amdgcn_mfma_f32_16x16x32_bf16(af[mi], bfr[ni], g[mi][ni], 0, 0, 0);
  }
  __syncthreads();   // all CB reads done before M overwrites it

  // mask -> M (overwrites CB)
#pragma unroll
  for (int mi = 0; mi < 2; ++mi) {
#pragma unroll
    for (int ni = 0; ni < 8; ++ni) {
      const int s = ni * 16 + la;
#pragma unroll
      for (int r = 0; r < 4; ++r) {
        const int t = w * 32 + mi * 16 + lb * 4 + r;
        float mv = 0.f;
        if (s <= t) mv = g[mi][ni][r] * __expf(cumS[t] - cumS[s]) * dtS[s];
        if (s == t) mv += dp;
        *(unsigned short*)CBB(t, s * 2) = f2bf(mv);
      }
    }
  }
  __syncthreads();   // M visible to all waves

  // Y1 = M @ X : K = 128
  f32x4_t y1[2][4];
#pragma unroll
  for (int mi = 0; mi < 2; ++mi)
#pragma unroll
    for (int ni = 0; ni < 4; ++ni) y1[mi][ni] = (f32x4_t){0.f, 0.f, 0.f, 0.f};
#pragma unroll
  for (int ks = 0; ks < 4; ++ks) {
    bf16x8_t af[2], xf[4];
#pragma unroll
    for (int mi = 0; mi < 2; ++mi)
      af[mi] = *(const bf16x8_t*)CBB(w * 32 + mi * 16 + la, ks * 64 + lb * 16);
#pragma unroll
    for (int ni = 0; ni < 4; ++ni)
      xf[ni] = *(const bf16x8_t*)XTB(ni * 16 + la, ks * 64 + lb * 16);
#pragma unroll
    for (int mi = 0; mi < 2; ++mi)
#pragma unroll
      for (int ni = 0; ni < 4; ++ni)
        y1[mi][ni] = __builtin_amdgcn_mfma_f32_16x16x32_bf16(af[mi], xf[ni], y1[mi][ni], 0, 0, 0);
  }
  // write y while M region is being recycled
  unsigned short* yg = y + row0 * ldy + h * 64;
#pragma unroll
  for (int mi = 0; mi < 2; ++mi)
#pragma unroll
    for (int ni = 0; ni < 4; ++ni)
#pragma unroll
      for (int r = 0; r < 4; ++r) {
        const int t = w * 32 + mi * 16 + lb * 4 + r;
        yg[(size_t)t * ldy + ni * 16 + la] = f2bf(y1[mi][ni][r]);
      }
  __syncthreads();   // Y1 done reading CB (M dead)

  // Btw = (w_s * B)^T into CB rows 0..63 (global re-read, L2-hot)
  {
    const int s = tid >> 1, q = tid & 1;
    const unsigned short* src = xr + (size_t)s * CONVD + 2048;
    const float ww = wS[s];
#pragma unroll
    for (int j = 0; j < 4; ++j) {
      const int c0 = q * 32 + j * 8;
      const u16x8_t bv = *(const u16x8_t*)(src + c0);
#pragma unroll
      for (int e = 0; e < 8; ++e)
        *(unsigned short*)CBB(c0 + e, s * 2) = f2bf(bf2f(bv[e]) * ww);
    }
  }
  __syncthreads();   // Btw visible

  // Hloc = X^T @ Btw^T : K = 128
  f32x4_t hacc[4];
#pragma unroll
  for (int ni = 0; ni < 4; ++ni) hacc[ni] = (f32x4_t){0.f, 0.f, 0.f, 0.f};
#pragma unroll
  for (int ks = 0; ks < 4; ++ks) {
    const bf16x8_t af = *(const bf16x8_t*)XTB(w * 16 + la, ks * 64 + lb * 16);
    bf16x8_t bw[4];
#pragma unroll
    for (int ni = 0; ni < 4; ++ni)
      bw[ni] = *(const bf16x8_t*)CBB(ni * 16 + la, ks * 64 + lb * 16);
#pragma unroll
    for (int ni = 0; ni < 4; ++ni)
      hacc[ni] = __builtin_amdgcn_mfma_f32_16x16x32_bf16(af, bw[ni], hacc[ni], 0, 0, 0);
  }

  unsigned short* Hg = H + ((size_t)ch * 128 + bh) * 4096;
#pragma unroll
  for (int ni = 0; ni < 4; ++ni)
#pragma unroll
    for (int r = 0; r < 4; ++r) {
      const int p = w * 16 + lb * 4 + r;
      Hg[p * 64 + ni * 16 + la] = f2bf(hacc[ni][r]);
    }
}

// ---------------- scan pass 2: segment-summary scan (end-state -> start-state) ----------------
__global__ __launch_bounds__(256) void scan2_kernel(
    unsigned short* __restrict__ H, const float* __restrict__ cumdec)
{
  const int bh = blockIdx.x;
  const int e = threadIdx.x * 16;
  float hs[16];
#pragma unroll
  for (int k = 0; k < 16; ++k) hs[k] = 0.f;
  unsigned short* Hb = H + (size_t)bh * 4096 + e;
  const float* cd = cumdec + (size_t)bh * LSEQ;
  for (int s = 0; s < SEGS; ++s) {
    unsigned short* p = Hb + (size_t)s * 128 * 4096;
    const float rseg = cd[s * TSEG + TSEG - 1];
    u16x8_t v0 = *(u16x8_t*)p, v1 = *(u16x8_t*)(p + 8);
    u16x8_t w0, w1;
#pragma unroll
    for (int k = 0; k < 8; ++k) {
      const float tmp = bf2f(v0[k]);
      w0[k] = f2bf(hs[k]);
      hs[k] = fmaf(rseg, hs[k], tmp);
    }
#pragma unroll
    for (int k = 0; k < 8; ++k) {
      const float tmp = bf2f(v1[k]);
      w1[k] = f2bf(hs[k + 8]);
      hs[k + 8] = fmaf(rseg, hs[k + 8], tmp);
    }
    *(u16x8_t*)p = w0;
    *(u16x8_t*)(p + 8) = w1;
  }
}

// ---------------- scan pass 3 (MFMA): Y += diag(cumdec) * C @ Hstart^T ----------------
#define CSB(t, cbyte) ((char*)Cs + (t) * 128 + ((cbyte) ^ (((t) & 7) << 4)))
#define HSB(p, cbyte) ((char*)Hs + (p) * 128 + ((cbyte) ^ (((p) & 7) << 4)))
__global__ __launch_bounds__(256) void scan3_mfma(
    const unsigned short* __restrict__ xbc,
    const float* __restrict__ cumdec,
    const unsigned short* __restrict__ H,
    unsigned short* __restrict__ y, int ldy)
{
  __shared__ unsigned short Cs[TSEG * 64];  // 16KB
  __shared__ unsigned short Hs[64 * 64];    // 8KB
  __shared__ float cdS[TSEG];
  const int id = blockIdx.x;
  const int bh = id / 15, ch = id % 15 + 1;
  const int b = bh >> 5, h = bh & 31;
  const int tid = threadIdx.x, w = tid >> 6, l = tid & 63;
  const int la = l & 15, lb = l >> 4;
  const size_t row0 = (size_t)b * LSEQ + (size_t)ch * TSEG;
  const unsigned short* xr = xbc + row0 * CONVD;
  {
    const int t = tid >> 1, q = tid & 1;
#pragma unroll
    for (int j = 0; j < 4; ++j) {
      const int c0 = q * 32 + j * 8;
      *(u16x8_t*)CSB(t, c0 * 2) = *(const u16x8_t*)(xr + (size_t)t * CONVD + 2112 + c0);
    }
  }
  {
    const int p = tid >> 2, q = tid & 3;
    const unsigned short* hsrc = H + ((size_t)ch * 128 + bh) * 4096 + p * 64;
#pragma unroll
    for (int j = 0; j < 2; ++j) {
      const int c0 = q * 16 + j * 8;
      *(u16x8_t*)HSB(p, c0 * 2) = *(const u16x8_t*)(hsrc + c0);
    }
  }
  if (tid < TSEG) cdS[tid] = cumdec[(size_t)bh * LSEQ + (size_t)ch * TSEG + tid];
  __syncthreads();
  f32x4_t acc[2][4];
#pragma unroll
  for (int mi = 0; mi < 2; ++mi)
#pragma unroll
    for (int ni = 0; ni < 4; ++ni) acc[mi][ni] = (f32x4_t){0.f, 0.f, 0.f, 0.f};
#pragma unroll
  for (int ks = 0; ks < 2; ++ks) {
    bf16x8_t af[2], bfr[4];
#pragma unroll
    for (int mi = 0; mi < 2; ++mi)
      af[mi] = *(const bf16x8_t*)CSB(w * 32 + mi * 16 + la, ks * 64 + lb * 16);
#pragma unroll
    for (int ni = 0; ni < 4; ++ni)
      bfr[ni] = *(const bf16x8_t*)HSB(ni * 16 + la, ks * 64 + lb * 16);
#pragma unroll
    for (int mi = 0; mi < 2; ++mi)
#pragma unroll
      for (int ni = 0; ni < 4; ++ni)
        acc[mi][ni] = __builtin_amdgcn_mfma_f32_16x16x32_bf16(af[mi], bfr[ni], acc[mi][ni], 0, 0, 0);
  }
  unsigned short* yg = y + row0 * ldy + h * 64;
#pragma unroll
  for (int mi = 0; mi < 2; ++mi)
#pragma unroll
    for (int ni = 0; ni < 4; ++ni)
#pragma unroll
      for (int r = 0; r < 4; ++r) {
        const int t = w * 32 + mi * 16 + lb * 4 + r;
        unsigned short* yp = yg + (size_t)t * ldy + ni * 16 + la;
        *yp = f2bf(bf2f(*yp) + acc[mi][ni][r] * cdS[t]);
      }
}

// ---------------- y * silu(z), RMSNorm, * norm_w -> bf16 (wave-per-row) ---------
__global__ __launch_bounds__(256) void gate_kernel(const unsigned short* __restrict__ zx,
    const float* __restrict__ nw, unsigned short* __restrict__ out)
{
  const int r = blockIdx.x * 4 + (threadIdx.x >> 6);
  const int l = threadIdx.x & 63;
  const size_t rb = (size_t)r * NPROJ;
  float v[4][8];
  float ss = 0.f;
#pragma unroll
  for (int j = 0; j < 4; ++j) {
    const u16x8_t zv = *(const u16x8_t*)(zx + rb + (l + 64 * j) * 8);
    const u16x8_t yv = *(const u16x8_t*)(zx + rb + 2048 + (l + 64 * j) * 8);
#pragma unroll
    for (int e = 0; e < 8; ++e) {
      v[j][e] = bf2f(yv[e]) * siluf(bf2f(zv[e]));
      ss += v[j][e] * v[j][e];
    }
  }
  const float rs = rsqrtf(wave_sum(ss) * (1.f / DINNER) + EPSV);
#pragma unroll
  for (int j = 0; j < 4; ++j) {
    const float4 w0 = ((const float4*)nw)[(l + 64 * j) * 2];
    const float4 w1 = ((const float4*)nw)[(l + 64 * j) * 2 + 1];
    u16x8_t o;
    o[0] = f2bf(v[j][0] * rs * w0.x); o[1] = f2bf(v[j][1] * rs * w0.y);
    o[2] = f2bf(v[j][2] * rs * w0.z); o[3] = f2bf(v[j][3] * rs * w0.w);
    o[4] = f2bf(v[j][4] * rs * w1.x); o[5] = f2bf(v[j][5] * rs * w1.y);
    o[6] = f2bf(v[j][6] * rs * w1.z); o[7] = f2bf(v[j][7] * rs * w1.w);
    *(u16x8_t*)(out + (size_t)r * DINNER + (l + 64 * j) * 8) = o;
  }
}

// ---------------- launch ----------------
extern "C" void kernel_launch(void* const* d_in, const int* in_sizes, int n_in,
                              void* d_out, int out_size, void* d_ws, size_t ws_size,
                              hipStream_t stream) {
  (void)in_sizes; (void)n_in; (void)out_size; (void)ws_size;
  const float* x_in    = (const float*)d_in[0];
  const float* ln_w    = (const float*)d_in[1];
  const float* ln_b    = (const float*)d_in[2];
  const float* in_w    = (const float*)d_in[3];
  const float* conv_w  = (const float*)d_in[4];
  const float* conv_b  = (const float*)d_in[5];
  const float* dt_bias = (const float*)d_in[6];
  const float* A_log   = (const float*)d_in[7];
  const float* Dp      = (const float*)d_in[8];
  const float* norm_w  = (const float*)d_in[9];
  const float* out_w   = (const float*)d_in[10];
  float* xout = (float*)d_out;

  char* ws = (char*)d_ws;
  unsigned short* zxb  = (unsigned short*)ws;                 // 69,730,304
  char* r1 = ws + (size_t)NROWS * NPROJ * 2;
  unsigned short* xn   = (unsigned short*)r1;
  unsigned short* xbcb = (unsigned short*)r1;
  unsigned short* ybf  = (unsigned short*)r1;
  char* wth = r1 + (size_t)NROWS * CONVD * 2;                 // +35,651,584
  unsigned short* inwT = (unsigned short*)wth;
  unsigned short* owT  = (unsigned short*)wth;
  unsigned short* Hbuf = (unsigned short*)wth;                // 16,777,216
  float* cumdec = (float*)(wth + (size_t)SEGS * 128 * 4096 * 2);

  hipMemcpyAsync(xout, x_in, (size_t)NROWS * DMODEL * 4, hipMemcpyDeviceToDevice, stream);

  for (int i = 0; i < 4; ++i) {
    ln_kernel<<<NROWS / 4, 256, 0, stream>>>(xout, ln_w + i * DMODEL, ln_b + i * DMODEL, xn);
    transpose_bf16<<<dim3(133, 32), dim3(32, 32), 0, stream>>>(
        in_w + (size_t)i * DMODEL * NPROJ, inwT, DMODEL, NPROJ);
    gemm_bf16<<<dim3(64, 34), 256, 0, stream>>>(xn, inwT, zxb, NPROJ, DMODEL, NPROJ);
    conv_kernel<<<dim3(2, NROWS / 4), 256, 0, stream>>>(
        zxb, conv_w + (size_t)i * 4 * CONVD, conv_b + i * CONVD, xbcb);
    ssd_chunk_kernel<<<128 * SEGS, 256, 0, stream>>>(xbcb, zxb,
        dt_bias + i * NH, A_log + i * NH, Dp + i * NH,
        zxb + 2048, NPROJ, Hbuf, cumdec);
    scan2_kernel<<<128, 256, 0, stream>>>(Hbuf, cumdec);
    scan3_mfma<<<128 * 15, 256, 0, stream>>>(xbcb, cumdec, Hbuf, zxb + 2048, NPROJ);
    gate_kernel<<<NROWS / 4, 256, 0, stream>>>(zxb, norm_w + i * DINNER, ybf);
    transpose_bf16<<<dim3(32, 64), dim3(32, 32), 0, stream>>>(
        out_w + (size_t)i * DINNER * DMODEL, owT, DINNER, DMODEL);
    gemm_res<<<dim3(64, 8), 256, 0, stream>>>(ybf, owT, xout, DMODEL, DINNER, DMODEL);
  }
}

// Round 21
// 1290.369 us; speedup vs baseline: 1.0520x; 1.0016x over previous
//
#include <hip/hip_runtime.h>
#include <math.h>

#define LSEQ   2048
#define NROWS  8192      // B*L = 4*2048
#define DMODEL 1024
#define DINNER 2048
#define NH     32
#define CONVD  2176
#define NPROJ  4256
#define NPROJ_PAD 4352
#define EPSV   1e-5f
#define SEGS   16
#define TSEG   128       // chunk length

typedef __bf16 bf16x8_t __attribute__((ext_vector_type(8)));
typedef float f32x4_t __attribute__((ext_vector_type(4)));
typedef unsigned short u16x8_t __attribute__((ext_vector_type(8)));
typedef unsigned short u16x4_t __attribute__((ext_vector_type(4)));

__device__ __forceinline__ unsigned short f2bf(float f) {
  unsigned int u = __float_as_uint(f);
  u += 0x7fffu + ((u >> 16) & 1u);
  return (unsigned short)(u >> 16);
}
__device__ __forceinline__ float bf2f(unsigned short u) {
  return __uint_as_float((unsigned int)u << 16);
}
__device__ __forceinline__ float siluf(float x) { return x / (1.f + expf(-x)); }
__device__ __forceinline__ float wave_sum(float s) {
#pragma unroll
  for (int o = 1; o < 64; o <<= 1) s += __shfl_xor(s, o);
  return s;
}

// async global->LDS, 16B per lane. LDS dest must be wave-uniform base + lane*16.
__device__ __forceinline__ void gload16(const unsigned short* g, unsigned short* l) {
  __builtin_amdgcn_global_load_lds(
      (const __attribute__((address_space(1))) void*)g,
      (__attribute__((address_space(3))) void*)l, 16, 0, 0);
}

// ---------------- LayerNorm + cast to bf16 (wave-per-row, 4 rows/block) ---------
__global__ __launch_bounds__(256) void ln_kernel(const float* __restrict__ X,
    const float* __restrict__ w, const float* __restrict__ b,
    unsigned short* __restrict__ out)
{
  const int r = blockIdx.x * 4 + (threadIdx.x >> 6);
  const int l = threadIdx.x & 63;
  const float4* xr = (const float4*)(X + (size_t)r * DMODEL);
  float4 v[4];
#pragma unroll
  for (int j = 0; j < 4; ++j) v[j] = xr[l + 64 * j];
  float s = 0.f;
#pragma unroll
  for (int j = 0; j < 4; ++j) s += v[j].x + v[j].y + v[j].z + v[j].w;
  const float mu = wave_sum(s) * (1.f / DMODEL);
  float ss = 0.f;
#pragma unroll
  for (int j = 0; j < 4; ++j) {
    v[j].x -= mu; v[j].y -= mu; v[j].z -= mu; v[j].w -= mu;
    ss += v[j].x * v[j].x + v[j].y * v[j].y + v[j].z * v[j].z + v[j].w * v[j].w;
  }
  const float rs = rsqrtf(wave_sum(ss) * (1.f / DMODEL) + EPSV);
#pragma unroll
  for (int j = 0; j < 4; ++j) {
    const float4 wv = ((const float4*)w)[l + 64 * j];
    const float4 bv = ((const float4*)b)[l + 64 * j];
    u16x4_t o;
    o[0] = f2bf(v[j].x * rs * wv.x + bv.x);
    o[1] = f2bf(v[j].y * rs * wv.y + bv.y);
    o[2] = f2bf(v[j].z * rs * wv.z + bv.z);
    o[3] = f2bf(v[j].w * rs * wv.w + bv.w);
    *(u16x4_t*)(out + (size_t)r * DMODEL + (l + 64 * j) * 4) = o;
  }
}

// ---------------- transpose fp32 (K x N) -> bf16 (N x K) ----------------
__global__ void transpose_bf16(const float* __restrict__ W,
    unsigned short* __restrict__ WT, int K, int N)
{
  __shared__ float t[32][33];
  const int n0 = blockIdx.x * 32, k0 = blockIdx.y * 32;
  const int tx = threadIdx.x, ty = threadIdx.y;
  if (n0 + tx < N) t[ty][tx] = W[(size_t)(k0 + ty) * N + n0 + tx];
  __syncthreads();
  if (n0 + ty < N) WT[(size_t)(n0 + ty) * K + k0 + tx] = f2bf(t[tx][ty]);
}

#define WAITBAR(N) do {                                          \
    __builtin_amdgcn_sched_barrier(0);                           \
    asm volatile("s_waitcnt vmcnt(" #N ")" ::: "memory");        \
    __builtin_amdgcn_s_barrier();                                \
    __builtin_amdgcn_sched_barrier(0);                           \
  } while (0)

#define BAR do {                                 \
    __builtin_amdgcn_sched_barrier(0);           \
    __builtin_amdgcn_s_barrier();                \
    __builtin_amdgcn_sched_barrier(0);           \
  } while (0)

// ---------------- bf16 MFMA GEMM (128x128 tile, 2-deep counted-vmcnt) ----------
// C[M,N] = A[M,K] * BT[N,K]^T. 4 waves (2x2), 4x4 frags/wave. GEMM1 (bf16 out).
#define STAGE(BUF, KT) do {                                        \
    const int kt_ = (KT) * 32;                                     \
    gload16(Ag + kt_,                  sA##BUF + tid * 8);         \
    gload16(Ag + (size_t)64 * K + kt_, sA##BUF + 2048 + tid * 8);  \
    gload16(Bg + kt_,                  sB##BUF + tid * 8);         \
    gload16(Bg + (size_t)64 * K + kt_, sB##BUF + 2048 + tid * 8);  \
  } while (0)

#define COMPUTE(BUF) do {                                                           \
    bf16x8_t af[4], bfr[4];                                                         \
    _Pragma("unroll")                                                               \
    for (int mi = 0; mi < 4; ++mi)                                                  \
      af[mi] = *(const bf16x8_t*)(sA##BUF + (wr * 64 + mi * 16 + la) * 32 + lb * 8);\
    _Pragma("unroll")                                                               \
    for (int ni = 0; ni < 4; ++ni)                                                  \
      bfr[ni] = *(const bf16x8_t*)(sB##BUF + (wc * 64 + ni * 16 + la) * 32 + lb * 8);\
    _Pragma("unroll")                                                               \
    for (int mi = 0; mi < 4; ++mi)                                                  \
      _Pragma("unroll")                                                             \
      for (int ni = 0; ni < 4; ++ni)                                                \
        acc[mi][ni] = __builtin_amdgcn_mfma_f32_16x16x32_bf16(af[mi], bfr[ni],      \
                                                              acc[mi][ni], 0, 0, 0);\
  } while (0)

__global__ __launch_bounds__(256) void gemm_bf16(
    const unsigned short* __restrict__ A,
    const unsigned short* __restrict__ BT,
    unsigned short* __restrict__ Cb,
    int N, int K, int ldc)
{
  __shared__ __attribute__((aligned(16))) unsigned short sA0[128 * 32];
  __shared__ __attribute__((aligned(16))) unsigned short sA1[128 * 32];
  __shared__ __attribute__((aligned(16))) unsigned short sB0[128 * 32];
  __shared__ __attribute__((aligned(16))) unsigned short sB1[128 * 32];
  const int tid = threadIdx.x;
  const int w = tid >> 6, l = tid & 63;
  const int wr = w >> 1, wc = w & 1;
  const int la = l & 15, lb = l >> 4;
  const int m0 = blockIdx.x * 128, n0 = blockIdx.y * 128;
  f32x4_t acc[4][4];
#pragma unroll
  for (int i = 0; i < 4; ++i)
#pragma unroll
    for (int j = 0; j < 4; ++j) acc[i][j] = (f32x4_t){0.f, 0.f, 0.f, 0.f};

  const int r0 = tid >> 2, q0 = tid & 3;
  const unsigned short* Ag = A + (size_t)(m0 + r0) * K + q0 * 8;
  const unsigned short* Bg = BT + (size_t)(n0 + r0) * K + q0 * 8;
  const int nkt = K / 32;

  STAGE(0, 0);
  STAGE(1, 1);

  for (int t = 0; t < nkt - 2; t += 2) {
    WAITBAR(4);
    COMPUTE(0);
    BAR;
    STAGE(0, t + 2);
    WAITBAR(4);
    COMPUTE(1);
    BAR;
    STAGE(1, t + 3);
  }
  WAITBAR(4);
  COMPUTE(0);
  WAITBAR(0);
  COMPUTE(1);

#pragma unroll
  for (int mi = 0; mi < 4; ++mi) {
#pragma unroll
    for (int ni = 0; ni < 4; ++ni) {
      const int col = n0 + wc * 64 + ni * 16 + la;
      if (col < N) {
#pragma unroll
        for (int r = 0; r < 4; ++r) {
          const int row = m0 + wr * 64 + mi * 16 + lb * 4 + r;
          Cb[(size_t)row * ldc + col] = f2bf(acc[mi][ni][r]);
        }
      }
    }
  }
}

// ---------------- GEMM2: fp32 residual accumulate (non-atomic, full K) ----------
__global__ __launch_bounds__(256) void gemm_res(
    const unsigned short* __restrict__ A,
    const unsigned short* __restrict__ BT,
    float* __restrict__ Cf,
    int N, int K, int ldc)
{
  __shared__ __attribute__((aligned(16))) unsigned short sA0[128 * 32];
  __shared__ __attribute__((aligned(16))) unsigned short sA1[128 * 32];
  __shared__ __attribute__((aligned(16))) unsigned short sB0[128 * 32];
  __shared__ __attribute__((aligned(16))) unsigned short sB1[128 * 32];
  const int tid = threadIdx.x;
  const int w = tid >> 6, l = tid & 63;
  const int wr = w >> 1, wc = w & 1;
  const int la = l & 15, lb = l >> 4;
  const int m0 = blockIdx.x * 128, n0 = blockIdx.y * 128;
  f32x4_t acc[4][4];
#pragma unroll
  for (int i = 0; i < 4; ++i)
#pragma unroll
    for (int j = 0; j < 4; ++j) acc[i][j] = (f32x4_t){0.f, 0.f, 0.f, 0.f};

  const int r0 = tid >> 2, q0 = tid & 3;
  const unsigned short* Ag = A + (size_t)(m0 + r0) * K + q0 * 8;
  const unsigned short* Bg = BT + (size_t)(n0 + r0) * K + q0 * 8;
  const int nkt = K / 32;

  STAGE(0, 0);
  STAGE(1, 1);

  for (int t = 0; t < nkt - 2; t += 2) {
    WAITBAR(4);
    COMPUTE(0);
    BAR;
    STAGE(0, t + 2);
    WAITBAR(4);
    COMPUTE(1);
    BAR;
    STAGE(1, t + 3);
  }
  WAITBAR(4);
  COMPUTE(0);
  WAITBAR(0);
  COMPUTE(1);

#pragma unroll
  for (int mi = 0; mi < 4; ++mi) {
#pragma unroll
    for (int ni = 0; ni < 4; ++ni) {
      const int col = n0 + wc * 64 + ni * 16 + la;
      if (col < N) {
#pragma unroll
        for (int r = 0; r < 4; ++r) {
          const int row = m0 + wr * 64 + mi * 16 + lb * 4 + r;
          const size_t idx = (size_t)row * ldc + col;
          Cf[idx] += acc[mi][ni][r];
        }
      }
    }
  }
}

// ---------------- causal depthwise conv (width 4) + silu, 4 rows/block ----------
__global__ __launch_bounds__(256) void conv_kernel(const unsigned short* __restrict__ zx,
    const float* __restrict__ cw, const float* __restrict__ cb,
    unsigned short* __restrict__ out)
{
  const int c8 = (blockIdx.x * 256 + threadIdx.x) * 8;
  if (c8 >= CONVD) return;
  const int r4 = blockIdx.y * 4;           // first output row
  const int l4 = r4 & (LSEQ - 1);          // position within batch
  float vin[7][8];
#pragma unroll
  for (int i = 0; i < 7; ++i) {
    if (l4 - 3 + i >= 0) {
      const u16x8_t v = *(const u16x8_t*)(zx + (size_t)(r4 - 3 + i) * NPROJ + DINNER + c8);
#pragma unroll
      for (int e = 0; e < 8; ++e) vin[i][e] = bf2f(v[e]);
    } else {
#pragma unroll
      for (int e = 0; e < 8; ++e) vin[i][e] = 0.f;
    }
  }
  float wk[4][8], bias[8];
  {
    const float4 b0 = *(const float4*)(cb + c8);
    const float4 b1 = *(const float4*)(cb + c8 + 4);
    bias[0]=b0.x; bias[1]=b0.y; bias[2]=b0.z; bias[3]=b0.w;
    bias[4]=b1.x; bias[5]=b1.y; bias[6]=b1.z; bias[7]=b1.w;
#pragma unroll
    for (int k = 0; k < 4; ++k) {
      const float4 w0 = *(const float4*)(cw + k * CONVD + c8);
      const float4 w1 = *(const float4*)(cw + k * CONVD + c8 + 4);
      wk[k][0]=w0.x; wk[k][1]=w0.y; wk[k][2]=w0.z; wk[k][3]=w0.w;
      wk[k][4]=w1.x; wk[k][5]=w1.y; wk[k][6]=w1.z; wk[k][7]=w1.w;
    }
  }
#pragma unroll
  for (int rr = 0; rr < 4; ++rr) {
    float acc[8];
#pragma unroll
    for (int e = 0; e < 8; ++e) acc[e] = bias[e];
#pragma unroll
    for (int k = 0; k < 4; ++k)
#pragma unroll
      for (int e = 0; e < 8; ++e)
        acc[e] = fmaf(vin[rr + k][e], wk[k][e], acc[e]);
    u16x8_t o;
#pragma unroll
    for (int e = 0; e < 8; ++e) o[e] = f2bf(siluf(acc[e]));
    *(u16x8_t*)(out + (size_t)(r4 + rr) * CONVD + c8) = o;
  }
}

// ---------------- chunked SSD pass A (MFMA): intra-chunk Y + local end-state ----------------
// dt/softplus/log-decay folded in (wave 0). grid = 128 bh * 16 chunks, 256 thr.
// LDS 50KB (3 blocks/CU): Btw overlays CB rows 0..63 after Y1 consumes M.
#define CBB(t, cbyte)  ((char*)CB  + (t) * 256 + ((cbyte) ^ (((t) & 7) << 4)))
#define XTB(p, cbyte)  ((char*)Xt  + (p) * 256 + ((cbyte) ^ (((p) & 7) << 4)))
__global__ __launch_bounds__(256) void ssd_chunk_kernel(
    const unsigned short* __restrict__ xbc,   // NROWS x CONVD (xs | B | C)
    const unsigned short* __restrict__ zraw,  // NROWS x NPROJ (raw proj, dt col 4224+h)
    const float* __restrict__ dt_bias,
    const float* __restrict__ A_log,
    const float* __restrict__ Dp,
    unsigned short* __restrict__ y, int ldy,  // zxb+2048, NPROJ
    unsigned short* __restrict__ H,           // [SEGS][128][4096] (p*64+n)
    float* __restrict__ cumdec)               // [128][LSEQ]
{
  __shared__ unsigned short CB[TSEG * 128];   // C(0:64)|B(64:128) -> M -> Btw   32KB
  __shared__ unsigned short Xt[64 * TSEG];    // X^T [p][t]                      16KB
  __shared__ float cumS[TSEG], dtS[TSEG], wS[TSEG];
  const int id = blockIdx.x;
  const int bh = id >> 4, ch = id & 15;
  const int b = bh >> 5, h = bh & 31;
  const int tid = threadIdx.x;
  const int w = tid >> 6, l = tid & 63;
  const int la = l & 15, lb = l >> 4;
  const size_t row0 = (size_t)b * LSEQ + (size_t)ch * TSEG;
  const unsigned short* xr = xbc + row0 * CONVD;
  const float dp = Dp[h];

  // stage C, B (swizzled rows) and X^T
  {
    const int t = tid >> 1, q = tid & 1;
    const unsigned short* src = xr + (size_t)t * CONVD;
#pragma unroll
    for (int j = 0; j < 4; ++j) {
      const int c0 = q * 32 + j * 8;
      *(u16x8_t*)CBB(t, c0 * 2)       = *(const u16x8_t*)(src + 2112 + c0);  // C
      *(u16x8_t*)CBB(t, 128 + c0 * 2) = *(const u16x8_t*)(src + 2048 + c0);  // B
      const u16x8_t xv = *(const u16x8_t*)(src + h * 64 + c0);
#pragma unroll
      for (int e = 0; e < 8; ++e)
        *(unsigned short*)XTB(c0 + e, t * 2) = xv[e];
    }
  }
  if (w == 0) {  // dt softplus + log-decay + cumulative sums
    const float bias = dt_bias[h];
    const float aexp = __expf(A_log[h]);
    const float x0 = bf2f(zraw[(row0 + l) * NPROJ + (DINNER + CONVD) + h]) + bias;
    const float x1 = bf2f(zraw[(row0 + 64 + l) * NPROJ + (DINNER + CONVD) + h]) + bias;
    const float d0 = (x0 > 20.f) ? x0 : log1pf(__expf(x0));
    const float d1 = (x1 > 20.f) ? x1 : log1pf(__expf(x1));
    float a0 = -d0 * aexp;
    float a1 = -d1 * aexp;
#pragma unroll
    for (int o = 1; o < 64; o <<= 1) { const float u = __shfl_up(a0, o); if (l >= o) a0 += u; }
    const float tot0 = __shfl(a0, 63);
#pragma unroll
    for (int o = 1; o < 64; o <<= 1) { const float u = __shfl_up(a1, o); if (l >= o) a1 += u; }
    a1 += tot0;
    const float cT = __shfl(a1, 63);
    cumS[l] = a0;       cumS[64 + l] = a1;
    dtS[l] = d0;        dtS[64 + l] = d1;
    wS[l] = __expf(cT - a0) * d0;
    wS[64 + l] = __expf(cT - a1) * d1;
    float* cdg = cumdec + (size_t)bh * LSEQ + (size_t)ch * TSEG;
    cdg[l] = __expf(a0);
    cdg[64 + l] = __expf(a1);
  }
  __syncthreads();

  // G = C @ B^T : wave w owns rows [w*32, w*32+32)
  f32x4_t g[2][8];
#pragma unroll
  for (int mi = 0; mi < 2; ++mi)
#pragma unroll
    for (int ni = 0; ni < 8; ++ni) g[mi][ni] = (f32x4_t){0.f, 0.f, 0.f, 0.f};
#pragma unroll
  for (int ks = 0; ks < 2; ++ks) {
    bf16x8_t af[2], bfr[8];
#pragma unroll
    for (int mi = 0; mi < 2; ++mi)
      af[mi] = *(const bf16x8_t*)CBB(w * 32 + mi * 16 + la, ks * 64 + lb * 16);
#pragma unroll
    for (int ni = 0; ni < 8; ++ni)
      bfr[ni] = *(const bf16x8_t*)CBB(ni * 16 + la, 128 + ks * 64 + lb * 16);
#pragma unroll
    for (int mi = 0; mi < 2; ++mi)
#pragma unroll
      for (int ni = 0; ni < 8; ++ni)
        g[mi][ni] = __builtin_amdgcn_mfma_f32_16x16x32_bf16(af[mi], bfr[ni], g[mi][ni], 0, 0, 0);
  }
  __syncthreads();   // all CB reads done before M overwrites it

  // mask -> M (overwrites CB); wave-uniform skip of strictly-upper blocks
#pragma unroll
  for (int mi = 0; mi < 2; ++mi) {
    const int tmax = w * 32 + mi * 16 + 15;   // largest t in this (wave,mi) band
#pragma unroll
    for (int ni = 0; ni < 8; ++ni) {
      const int s = ni * 16 + la;
      if (ni * 16 > tmax) {                   // s > t for every lane: all zeros
#pragma unroll
        for (int r = 0; r < 4; ++r) {
          const int t = w * 32 + mi * 16 + lb * 4 + r;
          *(unsigned short*)CBB(t, s * 2) = 0;
        }
      } else {
#pragma unroll
        for (int r = 0; r < 4; ++r) {
          const int t = w * 32 + mi * 16 + lb * 4 + r;
          float mv = 0.f;
          if (s <= t) mv = g[mi][ni][r] * __expf(cumS[t] - cumS[s]) * dtS[s];
          if (s == t) mv += dp;
          *(unsigned short*)CBB(t, s * 2) = f2bf(mv);
        }
      }
    }
  }
  __syncthreads();   // M visible to all waves

  // Y1 = M @ X : K = 128
  f32x4_t y1[2][4];
#pragma unroll
  for (int mi = 0; mi < 2; ++mi)
#pragma unroll
    for (int ni = 0; ni < 4; ++ni) y1[mi][ni] = (f32x4_t){0.f, 0.f, 0.f, 0.f};
#pragma unroll
  for (int ks = 0; ks < 4; ++ks) {
    bf16x8_t af[2], xf[4];
#pragma unroll
    for (int mi = 0; mi < 2; ++mi)
      af[mi] = *(const bf16x8_t*)CBB(w * 32 + mi * 16 + la, ks * 64 + lb * 16);
#pragma unroll
    for (int ni = 0; ni < 4; ++ni)
      xf[ni] = *(const bf16x8_t*)XTB(ni * 16 + la, ks * 64 + lb * 16);
#pragma unroll
    for (int mi = 0; mi < 2; ++mi)
#pragma unroll
      for (int ni = 0; ni < 4; ++ni)
        y1[mi][ni] = __builtin_amdgcn_mfma_f32_16x16x32_bf16(af[mi], xf[ni], y1[mi][ni], 0, 0, 0);
  }
  // write y while M region is being recycled
  unsigned short* yg = y + row0 * ldy + h * 64;
#pragma unroll
  for (int mi = 0; mi < 2; ++mi)
#pragma unroll
    for (int ni = 0; ni < 4; ++ni)
#pragma unroll
      for (int r = 0; r < 4; ++r) {
        const int t = w * 32 + mi * 16 + lb * 4 + r;
        yg[(size_t)t * ldy + ni * 16 + la] = f2bf(y1[mi][ni][r]);
      }
  __syncthreads();   // Y1 done reading CB (M dead)

  // Btw = (w_s * B)^T into CB rows 0..63 (global re-read, L2-hot)
  {
    const int s = tid >> 1, q = tid & 1;
    const unsigned short* src = xr + (size_t)s * CONVD + 2048;
    const float ww = wS[s];
#pragma unroll
    for (int j = 0; j < 4; ++j) {
      const int c0 = q * 32 + j * 8;
      const u16x8_t bv = *(const u16x8_t*)(src + c0);
#pragma unroll
      for (int e = 0; e < 8; ++e)
        *(unsigned short*)CBB(c0 + e, s * 2) = f2bf(bf2f(bv[e]) * ww);
    }
  }
  __syncthreads();   // Btw visible

  // Hloc = X^T @ Btw^T : K = 128
  f32x4_t hacc[4];
#pragma unroll
  for (int ni = 0; ni < 4; ++ni) hacc[ni] = (f32x4_t){0.f, 0.f, 0.f, 0.f};
#pragma unroll
  for (int ks = 0; ks < 4; ++ks) {
    const bf16x8_t af = *(const bf16x8_t*)XTB(w * 16 + la, ks * 64 + lb * 16);
    bf16x8_t bw[4];
#pragma unroll
    for (int ni = 0; ni < 4; ++ni)
      bw[ni] = *(const bf16x8_t*)CBB(ni * 16 + la, ks * 64 + lb * 16);
#pragma unroll
    for (int ni = 0; ni < 4; ++ni)
      hacc[ni] = __builtin_amdgcn_mfma_f32_16x16x32_bf16(af, bw[ni], hacc[ni], 0, 0, 0);
  }

  unsigned short* Hg = H + ((size_t)ch * 128 + bh) * 4096;
#pragma unroll
  for (int ni = 0; ni < 4; ++ni)
#pragma unroll
    for (int r = 0; r < 4; ++r) {
      const int p = w * 16 + lb * 4 + r;
      Hg[p * 64 + ni * 16 + la] = f2bf(hacc[ni][r]);
    }
}

// ---------------- scan pass 2: segment-summary scan (end-state -> start-state) ----------------
__global__ __launch_bounds__(256) void scan2_kernel(
    unsigned short* __restrict__ H, const float* __restrict__ cumdec)
{
  const int bh = blockIdx.x;
  const int e = threadIdx.x * 16;
  float hs[16];
#pragma unroll
  for (int k = 0; k < 16; ++k) hs[k] = 0.f;
  unsigned short* Hb = H + (size_t)bh * 4096 + e;
  const float* cd = cumdec + (size_t)bh * LSEQ;
  for (int s = 0; s < SEGS; ++s) {
    unsigned short* p = Hb + (size_t)s * 128 * 4096;
    const float rseg = cd[s * TSEG + TSEG - 1];
    u16x8_t v0 = *(u16x8_t*)p, v1 = *(u16x8_t*)(p + 8);
    u16x8_t w0, w1;
#pragma unroll
    for (int k = 0; k < 8; ++k) {
      const float tmp = bf2f(v0[k]);
      w0[k] = f2bf(hs[k]);
      hs[k] = fmaf(rseg, hs[k], tmp);
    }
#pragma unroll
    for (int k = 0; k < 8; ++k) {
      const float tmp = bf2f(v1[k]);
      w1[k] = f2bf(hs[k + 8]);
      hs[k + 8] = fmaf(rseg, hs[k + 8], tmp);
    }
    *(u16x8_t*)p = w0;
    *(u16x8_t*)(p + 8) = w1;
  }
}

// ---------------- scan pass 3 (MFMA): Y += diag(cumdec) * C @ Hstart^T ----------------
#define CSB(t, cbyte) ((char*)Cs + (t) * 128 + ((cbyte) ^ (((t) & 7) << 4)))
#define HSB(p, cbyte) ((char*)Hs + (p) * 128 + ((cbyte) ^ (((p) & 7) << 4)))
__global__ __launch_bounds__(256) void scan3_mfma(
    const unsigned short* __restrict__ xbc,
    const float* __restrict__ cumdec,
    const unsigned short* __restrict__ H,
    unsigned short* __restrict__ y, int ldy)
{
  __shared__ unsigned short Cs[TSEG * 64];  // 16KB
  __shared__ unsigned short Hs[64 * 64];    // 8KB
  __shared__ float cdS[TSEG];
  const int id = blockIdx.x;
  const int bh = id / 15, ch = id % 15 + 1;
  const int b = bh >> 5, h = bh & 31;
  const int tid = threadIdx.x, w = tid >> 6, l = tid & 63;
  const int la = l & 15, lb = l >> 4;
  const size_t row0 = (size_t)b * LSEQ + (size_t)ch * TSEG;
  const unsigned short* xr = xbc + row0 * CONVD;
  {
    const int t = tid >> 1, q = tid & 1;
#pragma unroll
    for (int j = 0; j < 4; ++j) {
      const int c0 = q * 32 + j * 8;
      *(u16x8_t*)CSB(t, c0 * 2) = *(const u16x8_t*)(xr + (size_t)t * CONVD + 2112 + c0);
    }
  }
  {
    const int p = tid >> 2, q = tid & 3;
    const unsigned short* hsrc = H + ((size_t)ch * 128 + bh) * 4096 + p * 64;
#pragma unroll
    for (int j = 0; j < 2; ++j) {
      const int c0 = q * 16 + j * 8;
      *(u16x8_t*)HSB(p, c0 * 2) = *(const u16x8_t*)(hsrc + c0);
    }
  }
  if (tid < TSEG) cdS[tid] = cumdec[(size_t)bh * LSEQ + (size_t)ch * TSEG + tid];
  __syncthreads();
  f32x4_t acc[2][4];
#pragma unroll
  for (int mi = 0; mi < 2; ++mi)
#pragma unroll
    for (int ni = 0; ni < 4; ++ni) acc[mi][ni] = (f32x4_t){0.f, 0.f, 0.f, 0.f};
#pragma unroll
  for (int ks = 0; ks < 2; ++ks) {
    bf16x8_t af[2], bfr[4];
#pragma unroll
    for (int mi = 0; mi < 2; ++mi)
      af[mi] = *(const bf16x8_t*)CSB(w * 32 + mi * 16 + la, ks * 64 + lb * 16);
#pragma unroll
    for (int ni = 0; ni < 4; ++ni)
      bfr[ni] = *(const bf16x8_t*)HSB(ni * 16 + la, ks * 64 + lb * 16);
#pragma unroll
    for (int mi = 0; mi < 2; ++mi)
#pragma unroll
      for (int ni = 0; ni < 4; ++ni)
        acc[mi][ni] = __builtin_amdgcn_mfma_f32_16x16x32_bf16(af[mi], bfr[ni], acc[mi][ni], 0, 0, 0);
  }
  unsigned short* yg = y + row0 * ldy + h * 64;
#pragma unroll
  for (int mi = 0; mi < 2; ++mi)
#pragma unroll
    for (int ni = 0; ni < 4; ++ni)
#pragma unroll
      for (int r = 0; r < 4; ++r) {
        const int t = w * 32 + mi * 16 + lb * 4 + r;
        unsigned short* yp = yg + (size_t)t * ldy + ni * 16 + la;
        *yp = f2bf(bf2f(*yp) + acc[mi][ni][r] * cdS[t]);
      }
}

// ---------------- y * silu(z), RMSNorm, * norm_w -> bf16 (wave-per-row) ---------
__global__ __launch_bounds__(256) void gate_kernel(const unsigned short* __restrict__ zx,
    const float* __restrict__ nw, unsigned short* __restrict__ out)
{
  const int r = blockIdx.x * 4 + (threadIdx.x >> 6);
  const int l = threadIdx.x & 63;
  const size_t rb = (size_t)r * NPROJ;
  float v[4][8];
  float ss = 0.f;
#pragma unroll
  for (int j = 0; j < 4; ++j) {
    const u16x8_t zv = *(const u16x8_t*)(zx + rb + (l + 64 * j) * 8);
    const u16x8_t yv = *(const u16x8_t*)(zx + rb + 2048 + (l + 64 * j) * 8);
#pragma unroll
    for (int e = 0; e < 8; ++e) {
      v[j][e] = bf2f(yv[e]) * siluf(bf2f(zv[e]));
      ss += v[j][e] * v[j][e];
    }
  }
  const float rs = rsqrtf(wave_sum(ss) * (1.f / DINNER) + EPSV);
#pragma unroll
  for (int j = 0; j < 4; ++j) {
    const float4 w0 = ((const float4*)nw)[(l + 64 * j) * 2];
    const float4 w1 = ((const float4*)nw)[(l + 64 * j) * 2 + 1];
    u16x8_t o;
    o[0] = f2bf(v[j][0] * rs * w0.x); o[1] = f2bf(v[j][1] * rs * w0.y);
    o[2] = f2bf(v[j][2] * rs * w0.z); o[3] = f2bf(v[j][3] * rs * w0.w);
    o[4] = f2bf(v[j][4] * rs * w1.x); o[5] = f2bf(v[j][5] * rs * w1.y);
    o[6] = f2bf(v[j][6] * rs * w1.z); o[7] = f2bf(v[j][7] * rs * w1.w);
    *(u16x8_t*)(out + (size_t)r * DINNER + (l + 64 * j) * 8) = o;
  }
}

// ---------------- launch ----------------
extern "C" void kernel_launch(void* const* d_in, const int* in_sizes, int n_in,
                              void* d_out, int out_size, void* d_ws, size_t ws_size,
                              hipStream_t stream) {
  (void)in_sizes; (void)n_in; (void)out_size; (void)ws_size;
  const float* x_in    = (const float*)d_in[0];
  const float* ln_w    = (const float*)d_in[1];
  const float* ln_b    = (const float*)d_in[2];
  const float* in_w    = (const float*)d_in[3];
  const float* conv_w  = (const float*)d_in[4];
  const float* conv_b  = (const float*)d_in[5];
  const float* dt_bias = (const float*)d_in[6];
  const float* A_log   = (const float*)d_in[7];
  const float* Dp      = (const float*)d_in[8];
  const float* norm_w  = (const float*)d_in[9];
  const float* out_w   = (const float*)d_in[10];
  float* xout = (float*)d_out;

  char* ws = (char*)d_ws;
  unsigned short* zxb  = (unsigned short*)ws;                 // 69,730,304
  char* r1 = ws + (size_t)NROWS * NPROJ * 2;
  unsigned short* xn   = (unsigned short*)r1;
  unsigned short* xbcb = (unsigned short*)r1;
  unsigned short* ybf  = (unsigned short*)r1;
  char* wth = r1 + (size_t)NROWS * CONVD * 2;                 // +35,651,584
  unsigned short* inwT = (unsigned short*)wth;
  unsigned short* owT  = (unsigned short*)wth;
  unsigned short* Hbuf = (unsigned short*)wth;                // 16,777,216
  float* cumdec = (float*)(wth + (size_t)SEGS * 128 * 4096 * 2);

  hipMemcpyAsync(xout, x_in, (size_t)NROWS * DMODEL * 4, hipMemcpyDeviceToDevice, stream);

  for (int i = 0; i < 4; ++i) {
    ln_kernel<<<NROWS / 4, 256, 0, stream>>>(xout, ln_w + i * DMODEL, ln_b + i * DMODEL, xn);
    transpose_bf16<<<dim3(133, 32), dim3(32, 32), 0, stream>>>(
        in_w + (size_t)i * DMODEL * NPROJ, inwT, DMODEL, NPROJ);
    gemm_bf16<<<dim3(64, 34), 256, 0, stream>>>(xn, inwT, zxb, NPROJ, DMODEL, NPROJ);
    conv_kernel<<<dim3(2, NROWS / 4), 256, 0, stream>>>(
        zxb, conv_w + (size_t)i * 4 * CONVD, conv_b + i * CONVD, xbcb);
    ssd_chunk_kernel<<<128 * SEGS, 256, 0, stream>>>(xbcb, zxb,
        dt_bias + i * NH, A_log + i * NH, Dp + i * NH,
        zxb + 2048, NPROJ, Hbuf, cumdec);
    scan2_kernel<<<128, 256, 0, stream>>>(Hbuf, cumdec);
    scan3_mfma<<<128 * 15, 256, 0, stream>>>(xbcb, cumdec, Hbuf, zxb + 2048, NPROJ);
    gate_kernel<<<NROWS / 4, 256, 0, stream>>>(zxb, norm_w + i * DINNER, ybf);
    transpose_bf16<<<dim3(32, 64), dim3(32, 32), 0, stream>>>(
        out_w + (size_t)i * DINNER * DMODEL, owT, DINNER, DMODEL);
    gemm_res<<<dim3(64, 8), 256, 0, stream>>>(ybf, owT, xout, DMODEL, DINNER, DMODEL);
  }
}